// Round 1
// baseline (2972.444 us; speedup 1.0000x reference)
//
#include <hip/hip_runtime.h>
#include <hip/hip_bf16.h>

// Problem constants
#define NB 1024      // batch
#define NT 120       // seq len
#define NE 50        // embed
#define NH 300       // hidden
#define KX 64        // padded x K (50 -> 64): k-chunks 0..1
#define KH 320       // padded h K (300 -> 320): k-chunks 2..11
#define KT 384       // total padded K (12 chunks of 32)
#define HP 320       // padded h-cols per gate in WpT
#define NGRP 8       // row groups of 128 rows
#define NCOLB 19     // col blocks per group (19*16 = 304 >= 300 hidden cols)
#define NGEMM (NGRP * NCOLB)   // 152
#define GRID (NGEMM + NGRP)    // 160 (8 pred blocks)
#define WCOL_STRIDE 784        // LDS W col stride: 768B data + 16B pad (conflict-free b128)

typedef __bf16 bf16_t;
typedef __bf16 bf16x8 __attribute__((ext_vector_type(8)));
typedef float f32x4 __attribute__((ext_vector_type(4)));

__device__ __forceinline__ float sigmoidf_(float x) { return 1.0f / (1.0f + expf(-x)); }

// ---------------- prep kernels ----------------

// Build WpT[col][k]: col = g*HP + hc (g = gate i/j/f/o, hc = hidden col),
// k in padded space:
//   k 0..49    -> W row k        (x weights)
//   k 50..63   -> 0
//   k 64..363  -> W row k-14     (h weights for h[0..299])
//   k 364..383 -> 0
__global__ void prep_w(const float* __restrict__ W, bf16_t* __restrict__ WpT) {
    int gid = blockIdx.x * 256 + threadIdx.x;
    if (gid >= 4 * HP * KT) return;
    int k = gid % KT;
    int col = gid / KT;
    int g = col / HP, hc = col % HP;
    int kp = -1;
    if (k < 50) kp = k;
    else if (k >= 64 && k < 364) kp = k - 14;
    float v = 0.0f;
    if (kp >= 0 && hc < NH) v = W[(long)kp * 1200 + g * NH + hc];
    WpT[gid] = (bf16_t)v;
}

__global__ void prep_zero(uint4* __restrict__ p, int n) {
    int gid = blockIdx.x * 256 + threadIdx.x;
    if (gid < n) p[gid] = make_uint4(0u, 0u, 0u, 0u);
}

// Pre-gather embeddings for ALL timesteps: Xp[b][t][0..63] bf16 (padded 50->64).
__global__ void prep_x(const int* __restrict__ ids, const float* __restrict__ emb,
                       bf16_t* __restrict__ Xp) {
    int gid = blockIdx.x * 256 + threadIdx.x;   // (b*NT + t)*4 + s
    if (gid >= NB * NT * 4) return;
    int s = gid & 3;
    int bt = gid >> 2;
    int id = ids[bt];
    const float* er = emb + (long)id * NE;
    bf16_t* dst = Xp + (long)bt * KX + s * 16;
#pragma unroll
    for (int j = 0; j < 16; ++j) {
        int e = s * 16 + j;
        dst[j] = (bf16_t)((e < NE) ? er[e] : 0.0f);
    }
}

// ---------------- persistent LSTM kernel ----------------
// Blocks 0..151: GEMM blocks. blk = g*19 + c: group g (rows g*128..+127),
//   col block c (hidden cols c*16..c*16+15, all 4 gates). W slice in LDS,
//   C in registers, h exchanged via global double buffer + per-group flags.
// Blocks 152..159: prediction block for group g = blk-152; computes
//   preds[t] = h_t @ U + b2 for its 128 rows, one step behind the GEMM wave.
__global__ void __launch_bounds__(256) lstm_persist(
    const float* __restrict__ bl, const bf16_t* __restrict__ WpT,
    bf16_t* H0, bf16_t* H1,
    const bf16_t* __restrict__ Xp,
    unsigned* flgG, unsigned* flgP,
    const float* __restrict__ U, const float* __restrict__ b2,
    float* __restrict__ out)
{
    __shared__ __align__(16) unsigned char smem[64 * WCOL_STRIDE];   // 50176 B
    const int blk = blockIdx.x;
    const int tid = threadIdx.x;

    if (blk < NGEMM) {
        const int g = blk / NCOLB;
        const int c = blk % NCOLB;

        // ---- stage W slice into LDS (once): 64 cols (gate*16+mm), stride 784B
        for (int ch = tid; ch < 64 * 48; ch += 256) {
            int col = ch / 48, part = ch % 48;
            int gt = col >> 4, mm = col & 15;
            int hc = c * 16 + mm;
            const uint4* src = (const uint4*)(WpT + (long)(gt * HP + hc) * KT) + part;
            *(uint4*)(smem + col * WCOL_STRIDE + part * 16) = *src;
        }

        const int lane = tid & 63, wave = tid >> 6;
        const int m = lane & 15, quad = lane >> 4;
        const int rbase = g * 128 + wave * 32;       // this wave: rows rbase..rbase+31
        const int rowA0 = rbase + m;                 // A row, tile 0
        const int rowA1 = rbase + 16 + m;            // A row, tile 1
        const int hcOut = c * 16 + m;                // C/D col
        const bool colOK = (hcOut < NH);

        float bias[4] = {0.f, 0.f, 0.f, 0.f};
        if (colOK) {
#pragma unroll
            for (int gt = 0; gt < 4; ++gt) bias[gt] = bl[gt * NH + hcOut];
        }

        float cst[2][4] = {};                        // cell state, registers
        unsigned* gBase = flgG + (long)g * NT * 20;
        unsigned* pBase = flgP + (long)g * NT;

        __syncthreads();                             // W staged

        for (int t = 0; t < NT; ++t) {
            // x fragments: no dependency on other blocks -> load before barrier
            const bf16x8* xv0 = (const bf16x8*)(Xp + ((long)rowA0 * NT + t) * KX);
            const bf16x8* xv1 = (const bf16x8*)(Xp + ((long)rowA1 * NT + t) * KX);
            bf16x8 ax0[2], ax1[2];
#pragma unroll
            for (int kk = 0; kk < 2; ++kk) {
                ax0[kk] = xv0[kk * 4 + quad];
                ax1[kk] = xv1[kk * 4 + quad];
            }

            // ---- wait: group's h_{t-1} complete; pred done with buffer we overwrite
            if (t > 0) {
                if (wave == 0) {
                    const unsigned* gf = gBase + (long)(t - 1) * 20;
                    const unsigned* pf = pBase + (t - 2);
                    const bool needP = (t >= 2);
                    for (;;) {
                        unsigned v = 1u;
                        if (lane < NCOLB)
                            v = __hip_atomic_load(gf + lane, __ATOMIC_ACQUIRE,
                                                  __HIP_MEMORY_SCOPE_AGENT);
                        else if (lane == NCOLB && needP)
                            v = __hip_atomic_load(pf, __ATOMIC_ACQUIRE,
                                                  __HIP_MEMORY_SCOPE_AGENT);
                        if (__all(v != 0)) break;
                        __builtin_amdgcn_s_sleep(2);
                    }
                }
            }
            __syncthreads();

            const bf16_t* Hr = (t & 1) ? H1 : H0;
            bf16_t*       Hw = (t & 1) ? H0 : H1;

            // ---- issue h A-fragment loads early (independent)
            const bf16x8* hv0 = (const bf16x8*)(Hr + (long)rowA0 * KH);
            const bf16x8* hv1 = (const bf16x8*)(Hr + (long)rowA1 * KH);
            bf16x8 ah0[10], ah1[10];
#pragma unroll
            for (int i = 0; i < 10; ++i) {
                ah0[i] = hv0[i * 4 + quad];
                ah1[i] = hv1[i * 4 + quad];
            }

            f32x4 acc[2][4];
#pragma unroll
            for (int rt = 0; rt < 2; ++rt)
#pragma unroll
                for (int gt = 0; gt < 4; ++gt) acc[rt][gt] = (f32x4){0.f, 0.f, 0.f, 0.f};

            // x part: k-chunks 0..1
#pragma unroll
            for (int kk = 0; kk < 2; ++kk) {
#pragma unroll
                for (int gt = 0; gt < 4; ++gt) {
                    bf16x8 b = *(const bf16x8*)(smem + (gt * 16 + m) * WCOL_STRIDE
                                                + (kk * 4 + quad) * 16);
                    acc[0][gt] = __builtin_amdgcn_mfma_f32_16x16x32_bf16(ax0[kk], b, acc[0][gt], 0, 0, 0);
                    acc[1][gt] = __builtin_amdgcn_mfma_f32_16x16x32_bf16(ax1[kk], b, acc[1][gt], 0, 0, 0);
                }
            }
            // h part: k-chunks 2..11
#pragma unroll
            for (int kk = 2; kk < 12; ++kk) {
#pragma unroll
                for (int gt = 0; gt < 4; ++gt) {
                    bf16x8 b = *(const bf16x8*)(smem + (gt * 16 + m) * WCOL_STRIDE
                                                + (kk * 4 + quad) * 16);
                    acc[0][gt] = __builtin_amdgcn_mfma_f32_16x16x32_bf16(ah0[kk - 2], b, acc[0][gt], 0, 0, 0);
                    acc[1][gt] = __builtin_amdgcn_mfma_f32_16x16x32_bf16(ah1[kk - 2], b, acc[1][gt], 0, 0, 0);
                }
            }

            // ---- gates + state update (C/D: col = lane&15, row = quad*4 + r)
            if (colOK) {
#pragma unroll
                for (int rt = 0; rt < 2; ++rt) {
#pragma unroll
                    for (int r = 0; r < 4; ++r) {
                        int row = rbase + rt * 16 + quad * 4 + r;
                        float zi = acc[rt][0][r] + bias[0];
                        float zj = acc[rt][1][r] + bias[1];
                        float zf = acc[rt][2][r] + bias[2];
                        float zo = acc[rt][3][r] + bias[3];
                        float cn = cst[rt][r] * sigmoidf_(zf + 1.0f)
                                 + sigmoidf_(zi) * tanhf(zj);
                        cst[rt][r] = cn;
                        Hw[(long)row * KH + hcOut] = (bf16_t)(tanhf(cn) * sigmoidf_(zo));
                    }
                }
            }

            __syncthreads();   // drains each wave's vmcnt before barrier -> stores at L2
            if (tid == 0)
                __hip_atomic_store(gBase + (long)t * 20 + c, 1u,
                                   __ATOMIC_RELEASE, __HIP_MEMORY_SCOPE_AGENT);
        }
    } else {
        // ---------------- prediction block for group g ----------------
        const int g = blk - NGEMM;
        float* Us = (float*)smem;                    // U padded to 320 rows x 5
        for (int i = tid; i < 320 * 5; i += 256)
            Us[i] = (i < NH * 5) ? U[i] : 0.0f;
        unsigned* gBase = flgG + (long)g * NT * 20;
        unsigned* pBase = flgP + (long)g * NT;
        __syncthreads();

        for (int t = 0; t < NT; ++t) {
            if (tid < 64) {
                const unsigned* gf = gBase + (long)t * 20;
                for (;;) {
                    unsigned v = 1u;
                    if (tid < NCOLB)
                        v = __hip_atomic_load(gf + tid, __ATOMIC_ACQUIRE,
                                              __HIP_MEMORY_SCOPE_AGENT);
                    if (__all(v != 0)) break;
                    __builtin_amdgcn_s_sleep(2);
                }
            }
            __syncthreads();

            const bf16_t* Hc = (t & 1) ? H0 : H1;    // h_t (written at step t)
            for (int task = tid; task < 128 * 5; task += 256) {
                int rloc = task / 5, cls = task % 5;
                const bf16x8* hv = (const bf16x8*)(Hc + (long)(g * 128 + rloc) * KH);
                float s = 0.f;
#pragma unroll 4
                for (int kb = 0; kb < 40; ++kb) {    // 320 padded (pad h == 0)
                    bf16x8 h8 = hv[kb];
#pragma unroll
                    for (int j = 0; j < 8; ++j)
                        s += (float)h8[j] * Us[(kb * 8 + j) * 5 + cls];
                }
                out[(long)t * (NB * 5) + (g * 128 + rloc) * 5 + cls] = s + b2[cls];
            }

            __syncthreads();
            if (tid == 0)
                __hip_atomic_store(pBase + t, 1u,
                                   __ATOMIC_RELEASE, __HIP_MEMORY_SCOPE_AGENT);
        }
    }
}

// ---------------- launcher ----------------
extern "C" void kernel_launch(void* const* d_in, const int* in_sizes, int n_in,
                              void* d_out, int out_size, void* d_ws, size_t ws_size,
                              hipStream_t stream) {
    const int* ids   = (const int*)d_in[0];
    const float* emb = (const float*)d_in[1];
    const float* W   = (const float*)d_in[2];
    const float* bl  = (const float*)d_in[3];
    const float* U   = (const float*)d_in[4];
    const float* b2  = (const float*)d_in[5];
    float* out = (float*)d_out;

    // ws layout (16B-aligned, total ~18.1 MB):
    //   WpT   0         ..   983,040   (4*320*384*2)
    //   H0    983,040   .. 1,638,400   (1024*320*2)
    //   H1    1,638,400 .. 2,293,760
    //   flgG  2,293,760 .. 2,370,560   (8*120*20*4)
    //   flgP  2,370,560 .. 2,374,400   (8*120*4)
    //   Xp    2,374,400 .. 18,103,040  (1024*120*64*2)
    char* ws = (char*)d_ws;
    bf16_t*   WpT  = (bf16_t*)ws;
    bf16_t*   H0   = (bf16_t*)(ws + 983040);
    bf16_t*   H1   = (bf16_t*)(ws + 1638400);
    unsigned* flgG = (unsigned*)(ws + 2293760);
    unsigned* flgP = (unsigned*)(ws + 2370560);
    bf16_t*   Xp   = (bf16_t*)(ws + 2374400);

    prep_w<<<(4 * HP * KT + 255) / 256, 256, 0, stream>>>(W, WpT);
    // zero H0, H1, flgG, flgP (contiguous 1,391,360 B = 86,960 uint4)
    prep_zero<<<(86960 + 255) / 256, 256, 0, stream>>>((uint4*)(ws + 983040), 86960);
    prep_x<<<(NB * NT * 4 + 255) / 256, 256, 0, stream>>>(ids, emb, Xp);

    void* kargs[] = { (void*)&bl, (void*)&WpT, (void*)&H0, (void*)&H1, (void*)&Xp,
                      (void*)&flgG, (void*)&flgP, (void*)&U, (void*)&b2, (void*)&out };
    hipError_t err = hipLaunchCooperativeKernel((const void*)lstm_persist,
                                                dim3(GRID), dim3(256), kargs, 0, stream);
    if (err != hipSuccess) {
        // co-residency holds anyway: 160 blocks <= 256 CUs, 50.2 KB LDS, 4 waves
        lstm_persist<<<GRID, 256, 0, stream>>>(bl, WpT, H0, H1, Xp,
                                               flgG, flgP, U, b2, out);
    }
}

// Round 3
// 1991.688 us; speedup vs baseline: 1.4924x; 1.4924x over previous
//
#include <hip/hip_runtime.h>
#include <hip/hip_bf16.h>

// Problem constants
#define NB 1024      // batch
#define NT 120       // seq len
#define NE 50        // embed
#define NH 300       // hidden
#define KX 64        // padded x K (50 -> 64): k-chunks 0..1
#define KH 320       // padded h K (300 -> 320): k-chunks 2..11
#define KT 384       // total padded K (12 chunks of 32)
#define HP 320       // padded h-cols per gate in WpT
#define NGRP 8       // row groups of 128 rows
#define NCOLB 19     // col blocks per group (19*16 = 304 >= 300 hidden cols)
#define NGEMM (NGRP * NCOLB)   // 152
#define GRID (NGEMM + NGRP)    // 160 (8 pred blocks)
#define WCOL_STRIDE 784        // LDS W col stride: 768B data + 16B pad

typedef __bf16 bf16_t;
typedef __bf16 bf16x8 __attribute__((ext_vector_type(8)));
typedef float f32x4 __attribute__((ext_vector_type(4)));

__device__ __forceinline__ float sigmoidf_(float x) { return 1.0f / (1.0f + expf(-x)); }

// Device-coherent (agent-scope, sc1) 16B load as two relaxed 64-bit atomics.
// Compiler-generated -> vmcnt bookkeeping stays correct (round-2 lesson).
__device__ __forceinline__ bf16x8 coh_load8(const bf16_t* p) {
    const unsigned long long* q = (const unsigned long long*)p;
    union { unsigned long long u[2]; bf16x8 v; } t;
    t.u[0] = __hip_atomic_load(q,     __ATOMIC_RELAXED, __HIP_MEMORY_SCOPE_AGENT);
    t.u[1] = __hip_atomic_load(q + 1, __ATOMIC_RELAXED, __HIP_MEMORY_SCOPE_AGENT);
    return t.v;
}
// Device-coherent 16-bit store (relaxed agent atomic -> global_store_short sc1).
__device__ __forceinline__ void coh_store16(bf16_t* p, bf16_t h) {
    __hip_atomic_store((unsigned short*)p, __builtin_bit_cast(unsigned short, h),
                       __ATOMIC_RELAXED, __HIP_MEMORY_SCOPE_AGENT);
}

// ---------------- prep kernels ----------------

// Build WpT[col][k]: col = g*HP + hc (g = gate i/j/f/o, hc = hidden col),
// k in padded space:
//   k 0..49  -> W row k (x);  k 64..363 -> W row k-14 (h);  else 0
__global__ void prep_w(const float* __restrict__ W, bf16_t* __restrict__ WpT) {
    int gid = blockIdx.x * 256 + threadIdx.x;
    if (gid >= 4 * HP * KT) return;
    int k = gid % KT;
    int col = gid / KT;
    int g = col / HP, hc = col % HP;
    int kp = -1;
    if (k < 50) kp = k;
    else if (k >= 64 && k < 364) kp = k - 14;
    float v = 0.0f;
    if (kp >= 0 && hc < NH) v = W[(long)kp * 1200 + g * NH + hc];
    WpT[gid] = (bf16_t)v;
}

__global__ void prep_zero(uint4* __restrict__ p, int n) {
    int gid = blockIdx.x * 256 + threadIdx.x;
    if (gid < n) p[gid] = make_uint4(0u, 0u, 0u, 0u);
}

// Pre-gather embeddings for ALL timesteps: Xp[t][b][0..63] bf16 (padded 50->64).
// [t][b] layout -> each step reads one contiguous 128 KB slice (L2-friendly).
__global__ void prep_x(const int* __restrict__ ids, const float* __restrict__ emb,
                       bf16_t* __restrict__ Xp) {
    int gid = blockIdx.x * 256 + threadIdx.x;   // (b*NT + t)*4 + s
    if (gid >= NB * NT * 4) return;
    int s = gid & 3;
    int bt = gid >> 2;
    int b = bt / NT, t = bt % NT;
    int id = ids[bt];
    const float* er = emb + (long)id * NE;
    bf16_t* dst = Xp + ((long)t * NB + b) * KX + s * 16;
#pragma unroll
    for (int j = 0; j < 16; ++j) {
        int e = s * 16 + j;
        dst[j] = (bf16_t)((e < NE) ? er[e] : 0.0f);
    }
}

// ---------------- persistent LSTM kernel ----------------
// Blocks 0..151: GEMM blocks. blk = g*19 + c: group g (rows g*128..+127),
//   col block c (hidden cols c*16..+15, all 4 gates). W slice in LDS,
//   C in registers. h crosses blocks ONLY via relaxed agent atomics (sc1,
//   device-coherent) -> zero L2 invalidate/writeback in the steady state.
// Blocks 152..159: prediction block for group g = blk-152.
__global__ void __launch_bounds__(256, 1) lstm_persist(
    const float* __restrict__ bl, const bf16_t* __restrict__ WpT,
    bf16_t* H0, bf16_t* H1,
    const bf16_t* __restrict__ Xp,
    unsigned* flgG, unsigned* flgP,
    const float* __restrict__ U, const float* __restrict__ b2,
    float* __restrict__ out)
{
    __shared__ __align__(16) unsigned char smem[64 * WCOL_STRIDE];   // 50176 B
    const int blk = blockIdx.x;
    const int tid = threadIdx.x;

    if (blk < NGEMM) {
        const int g = blk / NCOLB;
        const int c = blk % NCOLB;

        // ---- stage W slice into LDS (once): 64 cols (gate*16+mm), stride 784B
        for (int ch = tid; ch < 64 * 48; ch += 256) {
            int col = ch / 48, part = ch % 48;
            int gt = col >> 4, mm = col & 15;
            int hc = c * 16 + mm;
            const uint4* src = (const uint4*)(WpT + (long)(gt * HP + hc) * KT) + part;
            *(uint4*)(smem + col * WCOL_STRIDE + part * 16) = *src;
        }

        const int lane = tid & 63, wave = tid >> 6;
        const int m = lane & 15, quad = lane >> 4;
        const int rbase = g * 128 + wave * 32;       // this wave: rows rbase..rbase+31
        const int rowA0 = rbase + m;                 // A row, tile 0
        const int rowA1 = rbase + 16 + m;            // A row, tile 1
        const int hcOut = c * 16 + m;                // C/D col
        const bool colOK = (hcOut < NH);

        float bias[4] = {0.f, 0.f, 0.f, 0.f};
        if (colOK) {
#pragma unroll
            for (int gt = 0; gt < 4; ++gt) bias[gt] = bl[gt * NH + hcOut];
        }

        float cst[2][4] = {};                        // cell state, registers
        unsigned* gBase = flgG + (long)g * NT * 20;
        unsigned* pBase = flgP + (long)g * NT;

        __syncthreads();                             // W staged

        for (int t = 0; t < NT; ++t) {
            // x fragments: plain cached loads (L2-resident, no coherence need)
            const bf16x8* xv0 = (const bf16x8*)(Xp + ((long)t * NB + rowA0) * KX);
            const bf16x8* xv1 = (const bf16x8*)(Xp + ((long)t * NB + rowA1) * KX);
            bf16x8 ax0[2], ax1[2];
#pragma unroll
            for (int kk = 0; kk < 2; ++kk) {
                ax0[kk] = xv0[kk * 4 + quad];
                ax1[kk] = xv1[kk * 4 + quad];
            }

            // ---- wait: group's h_{t-1} complete; pred done with buffer we overwrite
            if (t > 0) {
                if (wave == 0) {
                    const unsigned* gf = gBase + (long)(t - 1) * 20;
                    const unsigned* pf = pBase + (t - 2);
                    const bool needP = (t >= 2);
                    for (;;) {
                        unsigned v = 1u;
                        if (lane < NCOLB)
                            v = __hip_atomic_load(gf + lane, __ATOMIC_RELAXED,
                                                  __HIP_MEMORY_SCOPE_AGENT);
                        else if (lane == NCOLB && needP)
                            v = __hip_atomic_load(pf, __ATOMIC_RELAXED,
                                                  __HIP_MEMORY_SCOPE_AGENT);
                        if (__all(v != 0)) break;
                        __builtin_amdgcn_s_sleep(2);
                    }
                }
            }
            __syncthreads();
            __builtin_amdgcn_sched_barrier(0);       // nothing crosses the wait

            const bf16_t* Hr = (t & 1) ? H1 : H0;
            bf16_t*       Hw = (t & 1) ? H0 : H1;

            // ---- h A-fragments: device-coherent loads, batched for pipelining
            const bf16_t* h0p = Hr + (long)rowA0 * KH;
            const bf16_t* h1p = Hr + (long)rowA1 * KH;
            bf16x8 ah0[10], ah1[10];
#pragma unroll
            for (int i = 0; i < 10; ++i) {
                ah0[i] = coh_load8(h0p + (i * 4 + quad) * 8);
                ah1[i] = coh_load8(h1p + (i * 4 + quad) * 8);
            }
            __builtin_amdgcn_sched_barrier(0);       // keep loads issued ahead of MFMA

            f32x4 acc[2][4];
#pragma unroll
            for (int rt = 0; rt < 2; ++rt)
#pragma unroll
                for (int gt = 0; gt < 4; ++gt) acc[rt][gt] = (f32x4){0.f, 0.f, 0.f, 0.f};

            // x part: k-chunks 0..1
#pragma unroll
            for (int kk = 0; kk < 2; ++kk) {
#pragma unroll
                for (int gt = 0; gt < 4; ++gt) {
                    bf16x8 b = *(const bf16x8*)(smem + (gt * 16 + m) * WCOL_STRIDE
                                                + (kk * 4 + quad) * 16);
                    acc[0][gt] = __builtin_amdgcn_mfma_f32_16x16x32_bf16(ax0[kk], b, acc[0][gt], 0, 0, 0);
                    acc[1][gt] = __builtin_amdgcn_mfma_f32_16x16x32_bf16(ax1[kk], b, acc[1][gt], 0, 0, 0);
                }
            }
            // h part: k-chunks 2..11
#pragma unroll
            for (int kk = 2; kk < 12; ++kk) {
#pragma unroll
                for (int gt = 0; gt < 4; ++gt) {
                    bf16x8 b = *(const bf16x8*)(smem + (gt * 16 + m) * WCOL_STRIDE
                                                + (kk * 4 + quad) * 16);
                    acc[0][gt] = __builtin_amdgcn_mfma_f32_16x16x32_bf16(ah0[kk - 2], b, acc[0][gt], 0, 0, 0);
                    acc[1][gt] = __builtin_amdgcn_mfma_f32_16x16x32_bf16(ah1[kk - 2], b, acc[1][gt], 0, 0, 0);
                }
            }

            // ---- gates + state update (C/D: col = lane&15, row = quad*4 + r)
            // numerics identical to the round-1 passing kernel
            if (colOK) {
#pragma unroll
                for (int rt = 0; rt < 2; ++rt) {
#pragma unroll
                    for (int r = 0; r < 4; ++r) {
                        int row = rbase + rt * 16 + quad * 4 + r;
                        float zi = acc[rt][0][r] + bias[0];
                        float zj = acc[rt][1][r] + bias[1];
                        float zf = acc[rt][2][r] + bias[2];
                        float zo = acc[rt][3][r] + bias[3];
                        float cn = cst[rt][r] * sigmoidf_(zf + 1.0f)
                                 + sigmoidf_(zi) * tanhf(zj);
                        cst[rt][r] = cn;
                        coh_store16(Hw + (long)row * KH + hcOut,
                                    (bf16_t)(tanhf(cn) * sigmoidf_(zo)));
                    }
                }
            }

            __syncthreads();   // drains vmcnt(0): h stores at coherence point
            if (tid == 0)
                __hip_atomic_store(gBase + (long)t * 20 + c, 1u,
                                   __ATOMIC_RELAXED, __HIP_MEMORY_SCOPE_AGENT);
        }
    } else {
        // ---------------- prediction block for group g ----------------
        const int g = blk - NGEMM;
        float* Us   = (float*)smem;                  // 320 x 5 padded U (6400 B)
        float* psum = (float*)(smem + 6400);         // 128 x 2 x 5 partials (5120 B)
        for (int i = tid; i < 320 * 5; i += 256)
            Us[i] = (i < NH * 5) ? U[i] : 0.0f;
        float bb[5];
#pragma unroll
        for (int cc = 0; cc < 5; ++cc) bb[cc] = b2[cc];
        unsigned* gBase = flgG + (long)g * NT * 20;
        unsigned* pBase = flgP + (long)g * NT;
        __syncthreads();

        const int rloc = tid >> 1;                   // 0..127 (row in group)
        const int half = tid & 1;                    // k-half: 160 elems each

        for (int t = 0; t < NT; ++t) {
            if (tid < 64) {
                const unsigned* gf = gBase + (long)t * 20;
                for (;;) {
                    unsigned v = 1u;
                    if (tid < NCOLB)
                        v = __hip_atomic_load(gf + tid, __ATOMIC_RELAXED,
                                              __HIP_MEMORY_SCOPE_AGENT);
                    if (__all(v != 0)) break;
                    __builtin_amdgcn_s_sleep(2);
                }
            }
            __syncthreads();
            __builtin_amdgcn_sched_barrier(0);

            const bf16_t* Hc = (t & 1) ? H0 : H1;    // h_t (written at step t)
            const bf16_t* hp = Hc + (long)(g * 128 + rloc) * KH + half * 160;
            bf16x8 hreg[20];
#pragma unroll
            for (int i = 0; i < 20; ++i) hreg[i] = coh_load8(hp + i * 8);
            __builtin_amdgcn_sched_barrier(0);

            float s[5] = {0.f, 0.f, 0.f, 0.f, 0.f};
#pragma unroll 4
            for (int kb = 0; kb < 20; ++kb) {
#pragma unroll
                for (int j = 0; j < 8; ++j) {
                    float hv = (float)hreg[kb][j];
                    int k = half * 160 + kb * 8 + j;  // pad rows of Us are 0
#pragma unroll
                    for (int cc = 0; cc < 5; ++cc) s[cc] += hv * Us[k * 5 + cc];
                }
            }
#pragma unroll
            for (int cc = 0; cc < 5; ++cc) psum[(rloc * 2 + half) * 5 + cc] = s[cc];
            __syncthreads();

            if (tid < 128) {
#pragma unroll
                for (int cc = 0; cc < 5; ++cc) {
                    float v = psum[tid * 10 + cc] + psum[tid * 10 + 5 + cc] + bb[cc];
                    out[(long)t * (NB * 5) + (g * 128 + tid) * 5 + cc] = v;
                }
            }
            __syncthreads();   // psum consumed; all h reads of this t done
            if (tid == 0)
                __hip_atomic_store(pBase + t, 1u,
                                   __ATOMIC_RELAXED, __HIP_MEMORY_SCOPE_AGENT);
        }
    }
}

// ---------------- launcher ----------------
extern "C" void kernel_launch(void* const* d_in, const int* in_sizes, int n_in,
                              void* d_out, int out_size, void* d_ws, size_t ws_size,
                              hipStream_t stream) {
    const int* ids   = (const int*)d_in[0];
    const float* emb = (const float*)d_in[1];
    const float* W   = (const float*)d_in[2];
    const float* bl  = (const float*)d_in[3];
    const float* U   = (const float*)d_in[4];
    const float* b2  = (const float*)d_in[5];
    float* out = (float*)d_out;

    // ws layout (16B-aligned, total ~18.1 MB):
    //   WpT   0         ..   983,040   (4*320*384*2)
    //   H0    983,040   .. 1,638,400   (1024*320*2)
    //   H1    1,638,400 .. 2,293,760
    //   flgG  2,293,760 .. 2,370,560   (8*120*20*4)
    //   flgP  2,370,560 .. 2,374,400   (8*120*4)
    //   Xp    2,374,400 .. 18,103,040  (120*1024*64*2)
    char* ws = (char*)d_ws;
    bf16_t*   WpT  = (bf16_t*)ws;
    bf16_t*   H0   = (bf16_t*)(ws + 983040);
    bf16_t*   H1   = (bf16_t*)(ws + 1638400);
    unsigned* flgG = (unsigned*)(ws + 2293760);
    unsigned* flgP = (unsigned*)(ws + 2370560);
    bf16_t*   Xp   = (bf16_t*)(ws + 2374400);

    prep_w<<<(4 * HP * KT + 255) / 256, 256, 0, stream>>>(W, WpT);
    // zero H0, H1, flgG, flgP (contiguous 1,391,360 B = 86,960 uint4)
    // (end-of-kernel release flushes these to the coherence point before
    //  lstm_persist's device-scope reads)
    prep_zero<<<(86960 + 255) / 256, 256, 0, stream>>>((uint4*)(ws + 983040), 86960);
    prep_x<<<(NB * NT * 4 + 255) / 256, 256, 0, stream>>>(ids, emb, Xp);

    void* kargs[] = { (void*)&bl, (void*)&WpT, (void*)&H0, (void*)&H1, (void*)&Xp,
                      (void*)&flgG, (void*)&flgP, (void*)&U, (void*)&b2, (void*)&out };
    hipError_t err = hipLaunchCooperativeKernel((const void*)lstm_persist,
                                                dim3(GRID), dim3(256), kargs, 0, stream);
    if (err != hipSuccess) {
        // co-residency holds anyway: 160 blocks <= 256 CUs, 50.2 KB LDS
        lstm_persist<<<GRID, 256, 0, stream>>>(bl, WpT, H0, H1, Xp,
                                               flgG, flgP, U, b2, out);
    }
}

// Round 4
// 1952.064 us; speedup vs baseline: 1.5227x; 1.0203x over previous
//
#include <hip/hip_runtime.h>
#include <hip/hip_bf16.h>

// Problem constants
#define NB 1024      // batch
#define NT 120       // seq len
#define NE 50        // embed
#define NH 300       // hidden
#define KX 64        // padded x K (50 -> 64): k-chunks 0..1
#define KH 320       // padded h K (300 -> 320): k-chunks 2..11
#define KT 384       // total padded K (12 chunks of 32)
#define HP 320       // padded h-cols per gate in WpT
#define NGRP 8       // row groups of 128 rows
#define NCOLB 19     // col blocks per group (19*16 = 304 >= 300 hidden cols)
#define NGEMM (NGRP * NCOLB)   // 152 = total grid (pred folded into GEMM blocks)
#define WCOL_STRIDE 784        // LDS W col stride: 768B data + 16B pad

typedef __bf16 bf16_t;
typedef __bf16 bf16x8 __attribute__((ext_vector_type(8)));
typedef float f32x4 __attribute__((ext_vector_type(4)));

// Fast, saturation-safe gates (error ~1e-6, negligible vs bf16-h 0.0039):
//   x->-inf: exp->inf, 1/(1+inf)=0  ; x->+inf: exp->0, ->1
__device__ __forceinline__ float fsig(float x)  { return 1.0f / (1.0f + __expf(-x)); }
//   x->+inf: 2/1-1=1 ; x->-inf: 2/inf-1=-1
__device__ __forceinline__ float ftanh(float x) { return 2.0f / (1.0f + __expf(-2.0f * x)) - 1.0f; }

// Device-coherent (agent-scope, sc-bits) 16B load as two relaxed 64-bit atomics.
// Compiler-generated -> vmcnt bookkeeping stays correct.
__device__ __forceinline__ bf16x8 coh_load8(const bf16_t* p) {
    const unsigned long long* q = (const unsigned long long*)p;
    union { unsigned long long u[2]; bf16x8 v; } t;
    t.u[0] = __hip_atomic_load(q,     __ATOMIC_RELAXED, __HIP_MEMORY_SCOPE_AGENT);
    t.u[1] = __hip_atomic_load(q + 1, __ATOMIC_RELAXED, __HIP_MEMORY_SCOPE_AGENT);
    return t.v;
}
// Device-coherent 16-bit store.
__device__ __forceinline__ void coh_store16(bf16_t* p, bf16_t h) {
    __hip_atomic_store((unsigned short*)p, __builtin_bit_cast(unsigned short, h),
                       __ATOMIC_RELAXED, __HIP_MEMORY_SCOPE_AGENT);
}

// ---------------- prep kernels ----------------

// Build WpT[col][k]: col = g*HP + hc (g = gate i/j/f/o, hc = hidden col),
// k in padded space: k 0..49 -> W row k (x); k 64..363 -> W row k-14 (h); else 0
__global__ void prep_w(const float* __restrict__ W, bf16_t* __restrict__ WpT) {
    int gid = blockIdx.x * 256 + threadIdx.x;
    if (gid >= 4 * HP * KT) return;
    int k = gid % KT;
    int col = gid / KT;
    int g = col / HP, hc = col % HP;
    int kp = -1;
    if (k < 50) kp = k;
    else if (k >= 64 && k < 364) kp = k - 14;
    float v = 0.0f;
    if (kp >= 0 && hc < NH) v = W[(long)kp * 1200 + g * NH + hc];
    WpT[gid] = (bf16_t)v;
}

__global__ void prep_zero(uint4* __restrict__ p, int n) {
    int gid = blockIdx.x * 256 + threadIdx.x;
    if (gid < n) p[gid] = make_uint4(0u, 0u, 0u, 0u);
}

// Pre-gather embeddings for ALL timesteps: Xp[t][b][0..63] bf16 (padded 50->64).
__global__ void prep_x(const int* __restrict__ ids, const float* __restrict__ emb,
                       bf16_t* __restrict__ Xp) {
    int gid = blockIdx.x * 256 + threadIdx.x;   // (b*NT + t)*4 + s
    if (gid >= NB * NT * 4) return;
    int s = gid & 3;
    int bt = gid >> 2;
    int b = bt / NT, t = bt % NT;
    int id = ids[bt];
    const float* er = emb + (long)id * NE;
    bf16_t* dst = Xp + ((long)t * NB + b) * KX + s * 16;
#pragma unroll
    for (int j = 0; j < 16; ++j) {
        int e = s * 16 + j;
        dst[j] = (bf16_t)((e < NE) ? er[e] : 0.0f);
    }
}

// ---------------- persistent LSTM kernel ----------------
// 152 blocks, 512 threads (8 waves, 16 rows each). blk = g*19 + c:
// group g (rows g*128..+127), col block c (hidden cols c*16..+15, all 4 gates).
// W slice LDS-resident; C in registers; h exchanged via relaxed agent atomics;
// per-(group,step) flags; preds folded in: after publishing h, each block
// shfl-reduces its 16-col contribution to out[t] and atomicAdds (off-path).
__global__ void __launch_bounds__(512, 2) lstm_persist(
    const float* __restrict__ bl, const bf16_t* __restrict__ WpT,
    bf16_t* H0, bf16_t* H1,
    const bf16_t* __restrict__ Xp,
    unsigned* flgG,
    const float* __restrict__ U, const float* __restrict__ b2,
    float* __restrict__ out)
{
    __shared__ __align__(16) unsigned char smem[64 * WCOL_STRIDE];   // 50176 B
    const int blk = blockIdx.x;
    const int tid = threadIdx.x;
    const int g = blk / NCOLB;
    const int c = blk % NCOLB;

    // ---- stage W slice into LDS (once): 64 cols (gate*16+mm), stride 784B
    for (int ch = tid; ch < 64 * 48; ch += 512) {
        int col = ch / 48, part = ch % 48;
        int gt = col >> 4, mm = col & 15;
        int hc = c * 16 + mm;
        const uint4* src = (const uint4*)(WpT + (long)(gt * HP + hc) * KT) + part;
        *(uint4*)(smem + col * WCOL_STRIDE + part * 16) = *src;
    }

    const int lane = tid & 63, wave = tid >> 6;
    const int m = lane & 15, quad = lane >> 4;
    const int rbase = g * 128 + wave * 16;       // this wave: rows rbase..rbase+15
    const int rowA  = rbase + m;                 // A row
    const int hcOut = c * 16 + m;                // C/D col
    const bool colOK = (hcOut < NH);

    float bias[4] = {0.f, 0.f, 0.f, 0.f};
    float Ur[5]   = {0.f, 0.f, 0.f, 0.f, 0.f};
    if (colOK) {
#pragma unroll
        for (int gt = 0; gt < 4; ++gt) bias[gt] = bl[gt * NH + hcOut];
#pragma unroll
        for (int cc = 0; cc < 5; ++cc) Ur[cc] = U[hcOut * 5 + cc];
    }
    float b2v[5];
#pragma unroll
    for (int cc = 0; cc < 5; ++cc) b2v[cc] = b2[cc];

    float cst[4] = {0.f, 0.f, 0.f, 0.f};         // cell state (rows quad*4+r)
    unsigned* gBase = flgG + (long)g * NT * 20;

    __syncthreads();                             // W staged

    for (int t = 0; t < NT; ++t) {
        // x fragments: plain cached loads, independent of flags
        const bf16x8* xv = (const bf16x8*)(Xp + ((long)t * NB + rowA) * KX);
        bf16x8 ax[2];
#pragma unroll
        for (int kk = 0; kk < 2; ++kk) ax[kk] = xv[kk * 4 + quad];

        // ---- wait: all 19 sibling h-slices of step t-1 published
        if (t > 0) {
            if (wave == 0) {
                const unsigned* gf = gBase + (long)(t - 1) * 20;
                for (;;) {
                    unsigned v = 1u;
                    if (lane < NCOLB)
                        v = __hip_atomic_load(gf + lane, __ATOMIC_RELAXED,
                                              __HIP_MEMORY_SCOPE_AGENT);
                    if (__all(v != 0)) break;
                    __builtin_amdgcn_s_sleep(1);
                }
            }
        }
        __syncthreads();
        __builtin_amdgcn_sched_barrier(0);       // nothing crosses the wait

        const bf16_t* Hr = (t & 1) ? H1 : H0;
        bf16_t*       Hw = (t & 1) ? H0 : H1;

        // ---- h A-fragments: device-coherent loads, batched for pipelining
        const bf16_t* hp = Hr + (long)rowA * KH;
        bf16x8 ah[10];
#pragma unroll
        for (int i = 0; i < 10; ++i) ah[i] = coh_load8(hp + (i * 4 + quad) * 8);
        __builtin_amdgcn_sched_barrier(0);       // keep loads batched ahead of MFMA

        f32x4 acc[4];
#pragma unroll
        for (int gt = 0; gt < 4; ++gt) acc[gt] = (f32x4){0.f, 0.f, 0.f, 0.f};

        // x part: k-chunks 0..1
#pragma unroll
        for (int kk = 0; kk < 2; ++kk) {
#pragma unroll
            for (int gt = 0; gt < 4; ++gt) {
                bf16x8 b = *(const bf16x8*)(smem + (gt * 16 + m) * WCOL_STRIDE
                                            + (kk * 4 + quad) * 16);
                acc[gt] = __builtin_amdgcn_mfma_f32_16x16x32_bf16(ax[kk], b, acc[gt], 0, 0, 0);
            }
        }
        // h part: k-chunks 2..11
#pragma unroll
        for (int kk = 2; kk < 12; ++kk) {
#pragma unroll
            for (int gt = 0; gt < 4; ++gt) {
                bf16x8 b = *(const bf16x8*)(smem + (gt * 16 + m) * WCOL_STRIDE
                                            + (kk * 4 + quad) * 16);
                acc[gt] = __builtin_amdgcn_mfma_f32_16x16x32_bf16(ah[kk - 2], b, acc[gt], 0, 0, 0);
            }
        }

        // ---- gates + state update (C/D: col = lane&15, row = quad*4 + r)
        float hn_[4];
#pragma unroll
        for (int r = 0; r < 4; ++r) {
            float zi = acc[0][r] + bias[0];
            float zj = acc[1][r] + bias[1];
            float zf = acc[2][r] + bias[2];
            float zo = acc[3][r] + bias[3];
            float cn = cst[r] * fsig(zf + 1.0f) + fsig(zi) * ftanh(zj);
            cst[r] = cn;
            hn_[r] = ftanh(cn) * fsig(zo);
        }
        if (colOK) {
#pragma unroll
            for (int r = 0; r < 4; ++r) {
                int row = rbase + quad * 4 + r;
                coh_store16(Hw + (long)row * KH + hcOut, (bf16_t)hn_[r]);
            }
        }

        __syncthreads();   // all 8 waves' h stores drained (vmcnt 0 at barrier)
        if (tid == 0)
            __hip_atomic_store(gBase + (long)t * 20 + c, 1u,
                               __ATOMIC_RELAXED, __HIP_MEMORY_SCOPE_AGENT);

        // ---- folded prediction: this block's 16-col contribution to out[t].
        // Off the critical path (siblings already released by the flag above).
        {
            float p[4][5];
#pragma unroll
            for (int r = 0; r < 4; ++r)
#pragma unroll
                for (int cc = 0; cc < 5; ++cc) p[r][cc] = hn_[r] * Ur[cc];
            // reduce over the 16 col-lanes (m) within each quad group
#pragma unroll
            for (int k = 1; k < 16; k <<= 1) {
#pragma unroll
                for (int r = 0; r < 4; ++r)
#pragma unroll
                    for (int cc = 0; cc < 5; ++cc)
                        p[r][cc] += __shfl_xor(p[r][cc], k, 16);
            }
            if (m == 0) {
#pragma unroll
                for (int r = 0; r < 4; ++r) {
                    int row = rbase + quad * 4 + r;
                    float* o = out + (long)t * (NB * 5) + row * 5;
#pragma unroll
                    for (int cc = 0; cc < 5; ++cc) {
                        float v = p[r][cc] + (c == 0 ? b2v[cc] : 0.0f);
                        atomicAdd(o + cc, v);
                    }
                }
            }
        }
    }
}

// ---------------- launcher ----------------
extern "C" void kernel_launch(void* const* d_in, const int* in_sizes, int n_in,
                              void* d_out, int out_size, void* d_ws, size_t ws_size,
                              hipStream_t stream) {
    const int* ids   = (const int*)d_in[0];
    const float* emb = (const float*)d_in[1];
    const float* W   = (const float*)d_in[2];
    const float* bl  = (const float*)d_in[3];
    const float* U   = (const float*)d_in[4];
    const float* b2  = (const float*)d_in[5];
    float* out = (float*)d_out;

    // ws layout (16B-aligned, total ~18.1 MB):
    //   WpT   0         ..   983,040   (4*320*384*2)
    //   H0    983,040   .. 1,638,400   (1024*320*2)
    //   H1    1,638,400 .. 2,293,760
    //   flgG  2,293,760 .. 2,370,560   (8*120*20*4)
    //   Xp    2,370,560 .. 18,099,200  (120*1024*64*2)
    char* ws = (char*)d_ws;
    bf16_t*   WpT  = (bf16_t*)ws;
    bf16_t*   H0   = (bf16_t*)(ws + 983040);
    bf16_t*   H1   = (bf16_t*)(ws + 1638400);
    unsigned* flgG = (unsigned*)(ws + 2293760);
    bf16_t*   Xp   = (bf16_t*)(ws + 2370560);

    prep_w<<<(4 * HP * KT + 255) / 256, 256, 0, stream>>>(W, WpT);
    // zero H0, H1, flgG (contiguous 1,387,520 B = 86,720 uint4) — every launch
    prep_zero<<<(86720 + 255) / 256, 256, 0, stream>>>((uint4*)(ws + 983040), 86720);
    // zero out (atomic accumulation target): 120*1024*5*4 B = 153,600 uint4
    prep_zero<<<(153600 + 255) / 256, 256, 0, stream>>>((uint4*)out, 153600);
    prep_x<<<(NB * NT * 4 + 255) / 256, 256, 0, stream>>>(ids, emb, Xp);

    void* kargs[] = { (void*)&bl, (void*)&WpT, (void*)&H0, (void*)&H1, (void*)&Xp,
                      (void*)&flgG, (void*)&U, (void*)&b2, (void*)&out };
    hipError_t err = hipLaunchCooperativeKernel((const void*)lstm_persist,
                                                dim3(NGEMM), dim3(512), kargs, 0, stream);
    if (err != hipSuccess) {
        // co-residency holds anyway: 152 blocks <= 256 CUs, 50.2 KB LDS
        lstm_persist<<<NGEMM, 512, 0, stream>>>(bl, WpT, H0, H1, Xp,
                                                flgG, U, b2, out);
    }
}

// Round 5
// 1216.401 us; speedup vs baseline: 2.4436x; 1.6048x over previous
//
#include <hip/hip_runtime.h>
#include <hip/hip_bf16.h>

// Problem constants
#define NB 1024      // batch
#define NT 120       // seq len
#define NE 50        // embed
#define NH 300       // hidden
#define KX 64        // padded x K (50 -> 64): k-chunks 0..1
#define KH 320       // padded h K (300 -> 320): k-chunks 2..11
#define KT 384       // total padded K (12 chunks of 32)
#define HP 320       // padded h-cols per gate in WpT
#define NGRP 8       // row groups of 128 rows; group = blk & 7 (XCD-aligned)
#define NCOLB 19     // GEMM workers per group (19*16 = 304 >= 300 hidden cols)
#define ROLES 20     // 19 GEMM + 1 pred
#define GRID 160     // 8 groups * 20 roles; blk = role*8 + g
#define WCOL_STRIDE 784        // LDS W col stride: 768B data + 16B pad

typedef __bf16 bf16_t;
typedef __bf16 bf16x8 __attribute__((ext_vector_type(8)));
typedef float f32x4 __attribute__((ext_vector_type(4)));

// Fast, saturation-safe gates (error ~1e-6, negligible vs bf16-h rounding):
__device__ __forceinline__ float fsig(float x)  { return 1.0f / (1.0f + __expf(-x)); }
__device__ __forceinline__ float ftanh(float x) { return 2.0f / (1.0f + __expf(-2.0f * x)) - 1.0f; }

// ---- fallback (cross-XCD) transport: relaxed agent atomics (sc-bit, MALL) ----
__device__ __forceinline__ bf16x8 coh_load8(const bf16_t* p) {
    const unsigned long long* q = (const unsigned long long*)p;
    union { unsigned long long u[2]; bf16x8 v; } t;
    t.u[0] = __hip_atomic_load(q,     __ATOMIC_RELAXED, __HIP_MEMORY_SCOPE_AGENT);
    t.u[1] = __hip_atomic_load(q + 1, __ATOMIC_RELAXED, __HIP_MEMORY_SCOPE_AGENT);
    return t.v;
}
__device__ __forceinline__ void coh_store16(bf16_t* p, bf16_t h) {
    __hip_atomic_store((unsigned short*)p, __builtin_bit_cast(unsigned short, h),
                       __ATOMIC_RELAXED, __HIP_MEMORY_SCOPE_AGENT);
}
__device__ __forceinline__ void coh_storef(float* p, float v) {
    __hip_atomic_store((unsigned*)p, __builtin_bit_cast(unsigned, v),
                       __ATOMIC_RELAXED, __HIP_MEMORY_SCOPE_AGENT);
}
__device__ __forceinline__ float coh_loadf(const float* p) {
    unsigned u = __hip_atomic_load((const unsigned*)p,
                                   __ATOMIC_RELAXED, __HIP_MEMORY_SCOPE_AGENT);
    return __builtin_bit_cast(float, u);
}

// ---- local (same-XCD) transport helpers ----
// CU-local vector-L1 invalidate (sc0): subsequent plain loads are served by the
// XCD's L2, which producer write-through stores have reached (drained by the
// pre-flag __syncthreads vmcnt(0)). Trailing waitcnt is conservative-safe:
// extra waiting on compiler loads only over-waits, never under-waits.
__device__ __forceinline__ void inv_l1() {
    asm volatile("buffer_inv sc0\n\ts_waitcnt vmcnt(0)" ::: "memory");
}
// XCD id (HW_REG_XCC_ID, gfx940+; verified on MI355X toolchain).
__device__ __forceinline__ unsigned xcc_id() {
    unsigned x;
    asm volatile("s_getreg_b32 %0, hwreg(HW_REG_XCC_ID)" : "=s"(x));
    return x & 0xfu;
}

// ---------------- prep kernels ----------------
__global__ void prep_w(const float* __restrict__ W, bf16_t* __restrict__ WpT) {
    int gid = blockIdx.x * 256 + threadIdx.x;
    if (gid >= 4 * HP * KT) return;
    int k = gid % KT;
    int col = gid / KT;
    int g = col / HP, hc = col % HP;
    int kp = -1;
    if (k < 50) kp = k;
    else if (k >= 64 && k < 364) kp = k - 14;
    float v = 0.0f;
    if (kp >= 0 && hc < NH) v = W[(long)kp * 1200 + g * NH + hc];
    WpT[gid] = (bf16_t)v;
}

__global__ void prep_zero(uint4* __restrict__ p, int n) {
    int gid = blockIdx.x * 256 + threadIdx.x;
    if (gid < n) p[gid] = make_uint4(0u, 0u, 0u, 0u);
}

// Pre-gather embeddings: Xp[t][b][0..63] bf16 (padded 50->64).
__global__ void prep_x(const int* __restrict__ ids, const float* __restrict__ emb,
                       bf16_t* __restrict__ Xp) {
    int gid = blockIdx.x * 256 + threadIdx.x;   // (b*NT + t)*4 + s
    if (gid >= NB * NT * 4) return;
    int s = gid & 3;
    int bt = gid >> 2;
    int b = bt / NT, t = bt % NT;
    int id = ids[bt];
    const float* er = emb + (long)id * NE;
    bf16_t* dst = Xp + ((long)t * NB + b) * KX + s * 16;
#pragma unroll
    for (int j = 0; j < 16; ++j) {
        int e = s * 16 + j;
        dst[j] = (bf16_t)((e < NE) ? er[e] : 0.0f);
    }
}

// ---------------- persistent LSTM kernel ----------------
// blk = role*8 + g. Roles 0..18: GEMM worker for hidden cols role*16..+15
// (all 4 gates) of group g (batch rows g*128..+127). Role 19: pred block.
// Groups are data-independent; if a group's 20 blocks share an XCD (verified
// at runtime via XCC_ID), h/partials move through that XCD's L2 (plain
// write-through stores + inv_l1'd plain loads). Otherwise: agent atomics.
// Flags always go through relaxed agent atomics (proven).
__global__ void __launch_bounds__(512, 2) lstm_persist(
    const float* __restrict__ bl, const bf16_t* __restrict__ WpT,
    bf16_t* H0, bf16_t* H1,
    const bf16_t* __restrict__ Xp,
    unsigned* flgG, unsigned* flgP, float* part, unsigned* xcdA,
    const float* __restrict__ U, const float* __restrict__ b2,
    float* __restrict__ out)
{
    __shared__ __align__(16) unsigned char smem[64 * WCOL_STRIDE];   // 50176 B
    __shared__ int sLocalOK;
    const int blk = blockIdx.x;
    const int tid = threadIdx.x;
    const int g = blk & 7;
    const int c = blk >> 3;                      // role
    const int lane = tid & 63, wave = tid >> 6;

    // ---- publish my XCD; verify all 20 group members share it
    if (tid == 0)
        __hip_atomic_store(xcdA + blk, xcc_id() + 1u,
                           __ATOMIC_RELAXED, __HIP_MEMORY_SCOPE_AGENT);
    if (wave == 0) {
        unsigned v = 1u;
        for (;;) {
            if (lane < ROLES)
                v = __hip_atomic_load(xcdA + (lane * NGRP + g), __ATOMIC_RELAXED,
                                      __HIP_MEMORY_SCOPE_AGENT);
            if (__all(v != 0)) break;
            __builtin_amdgcn_s_sleep(1);
        }
        unsigned ref = __shfl(v, 0, 64);
        int ok = __all(lane >= ROLES || v == ref);
        if (lane == 0) sLocalOK = ok;
    }

    unsigned* gBase = flgG + (long)g * NT * ROLES;
    unsigned* pBase = flgP + (long)g * NT;

    if (c < NCOLB) {
        // ================= GEMM worker =================
        // stage W slice into LDS (once): 64 cols (gate*16+mm), stride 784B
        for (int ch = tid; ch < 64 * 48; ch += 512) {
            int col = ch / 48, pq = ch % 48;
            int gt = col >> 4, mm = col & 15;
            int hc = c * 16 + mm;
            const uint4* src = (const uint4*)(WpT + (long)(gt * HP + hc) * KT) + pq;
            *(uint4*)(smem + col * WCOL_STRIDE + pq * 16) = *src;
        }

        const int m = lane & 15, quad = lane >> 4;
        const int rbase = g * 128 + wave * 16;   // this wave: rows rbase..rbase+15
        const int rowA  = rbase + m;
        const int hcOut = c * 16 + m;
        const bool colOK = (hcOut < NH);

        float bias[4] = {0.f, 0.f, 0.f, 0.f};
        float Ur[5]   = {0.f, 0.f, 0.f, 0.f, 0.f};
        if (colOK) {
#pragma unroll
            for (int gt = 0; gt < 4; ++gt) bias[gt] = bl[gt * NH + hcOut];
#pragma unroll
            for (int cc = 0; cc < 5; ++cc) Ur[cc] = U[hcOut * 5 + cc];
        }
        float cst[4] = {0.f, 0.f, 0.f, 0.f};

        __syncthreads();                         // W staged + sLocalOK visible
        const bool localOK = (sLocalOK != 0);

        for (int t = 0; t < NT; ++t) {
            // x fragments: plain cached loads (fresh addresses each t)
            const bf16x8* xv = (const bf16x8*)(Xp + ((long)t * NB + rowA) * KX);
            bf16x8 ax[2];
#pragma unroll
            for (int kk = 0; kk < 2; ++kk) ax[kk] = xv[kk * 4 + quad];

            // wait: 19 sibling h-flags of t-1; pred done with partials (t-2)
            if (t > 0) {
                if (wave == 0) {
                    const unsigned* gf = gBase + (long)(t - 1) * ROLES;
                    const unsigned* pf = pBase + (t - 2);
                    const bool needP = (t >= 2);
                    for (;;) {
                        unsigned v = 1u;
                        if (lane < NCOLB)
                            v = __hip_atomic_load(gf + lane, __ATOMIC_RELAXED,
                                                  __HIP_MEMORY_SCOPE_AGENT);
                        else if (lane == NCOLB && needP)
                            v = __hip_atomic_load(pf, __ATOMIC_RELAXED,
                                                  __HIP_MEMORY_SCOPE_AGENT);
                        if (__all(v != 0)) break;
                        __builtin_amdgcn_s_sleep(1);
                    }
                }
            }
            __syncthreads();
            __builtin_amdgcn_sched_barrier(0);

            const bf16_t* Hr = (t & 1) ? H1 : H0;
            bf16_t*       Hw = (t & 1) ? H0 : H1;

            // ---- h A-fragments
            const bf16_t* hp = Hr + (long)rowA * KH;
            bf16x8 ah[10];
            if (localOK) {
                inv_l1();                        // L1 may hold stale h (t-2)
                const bf16x8* hv = (const bf16x8*)hp;
#pragma unroll
                for (int i = 0; i < 10; ++i) ah[i] = hv[i * 4 + quad];
            } else {
#pragma unroll
                for (int i = 0; i < 10; ++i) ah[i] = coh_load8(hp + (i * 4 + quad) * 8);
            }
            __builtin_amdgcn_sched_barrier(0);

            f32x4 acc[4];
#pragma unroll
            for (int gt = 0; gt < 4; ++gt) acc[gt] = (f32x4){0.f, 0.f, 0.f, 0.f};

            // x part: k-chunks 0..1
#pragma unroll
            for (int kk = 0; kk < 2; ++kk) {
#pragma unroll
                for (int gt = 0; gt < 4; ++gt) {
                    bf16x8 b = *(const bf16x8*)(smem + (gt * 16 + m) * WCOL_STRIDE
                                                + (kk * 4 + quad) * 16);
                    acc[gt] = __builtin_amdgcn_mfma_f32_16x16x32_bf16(ax[kk], b, acc[gt], 0, 0, 0);
                }
            }
            // h part: k-chunks 2..11
#pragma unroll
            for (int kk = 2; kk < 12; ++kk) {
#pragma unroll
                for (int gt = 0; gt < 4; ++gt) {
                    bf16x8 b = *(const bf16x8*)(smem + (gt * 16 + m) * WCOL_STRIDE
                                                + (kk * 4 + quad) * 16);
                    acc[gt] = __builtin_amdgcn_mfma_f32_16x16x32_bf16(ah[kk - 2], b, acc[gt], 0, 0, 0);
                }
            }

            // ---- gates + state update (C/D: col = lane&15, row = quad*4 + r)
            float hn_[4];
#pragma unroll
            for (int r = 0; r < 4; ++r) {
                float zi = acc[0][r] + bias[0];
                float zj = acc[1][r] + bias[1];
                float zf = acc[2][r] + bias[2];
                float zo = acc[3][r] + bias[3];
                float cn = cst[r] * fsig(zf + 1.0f) + fsig(zi) * ftanh(zj);
                cst[r] = cn;
                hn_[r] = ftanh(cn) * fsig(zo);
            }
            if (colOK) {
                if (localOK) {
#pragma unroll
                    for (int r = 0; r < 4; ++r)
                        Hw[(long)(rbase + quad * 4 + r) * KH + hcOut] = (bf16_t)hn_[r];
                } else {
#pragma unroll
                    for (int r = 0; r < 4; ++r)
                        coh_store16(Hw + (long)(rbase + quad * 4 + r) * KH + hcOut,
                                    (bf16_t)hn_[r]);
                }
            }

            // ---- fold this block's 16-col pred contribution -> partials
            {
                float p[4][5];
#pragma unroll
                for (int r = 0; r < 4; ++r)
#pragma unroll
                    for (int cc = 0; cc < 5; ++cc) p[r][cc] = hn_[r] * Ur[cc];
#pragma unroll
                for (int k = 1; k < 16; k <<= 1) {
#pragma unroll
                    for (int r = 0; r < 4; ++r)
#pragma unroll
                        for (int cc = 0; cc < 5; ++cc)
                            p[r][cc] += __shfl_xor(p[r][cc], k, 16);
                }
                if (m == 0) {
                    float* pb = part + (((long)(t & 1) * NGRP + g) * NCOLB + c) * 640;
#pragma unroll
                    for (int r = 0; r < 4; ++r) {
                        int rl = wave * 16 + quad * 4 + r;
                        if (localOK) {
#pragma unroll
                            for (int cc = 0; cc < 5; ++cc) pb[rl * 5 + cc] = p[r][cc];
                        } else {
#pragma unroll
                            for (int cc = 0; cc < 5; ++cc) coh_storef(pb + rl * 5 + cc, p[r][cc]);
                        }
                    }
                }
            }

            __syncthreads();   // all waves' h + partial stores drained (vmcnt 0)
            if (tid == 0)
                __hip_atomic_store(gBase + (long)t * ROLES + c, 1u,
                                   __ATOMIC_RELEASE, __HIP_MEMORY_SCOPE_AGENT);
        }
    } else {
        // ================= pred block: out[t] = sum_c partials + b2 =================
        float b2v[5];
#pragma unroll
        for (int cc = 0; cc < 5; ++cc) b2v[cc] = b2[cc];
        __syncthreads();
        const bool localOK = (sLocalOK != 0);

        for (int t = 0; t < NT; ++t) {
            if (wave == 0) {
                const unsigned* gf = gBase + (long)t * ROLES;
                for (;;) {
                    unsigned v = 1u;
                    if (lane < NCOLB)
                        v = __hip_atomic_load(gf + lane, __ATOMIC_RELAXED,
                                              __HIP_MEMORY_SCOPE_AGENT);
                    if (__all(v != 0)) break;
                    __builtin_amdgcn_s_sleep(1);
                }
            }
            __syncthreads();
            __builtin_amdgcn_sched_barrier(0);

            const float* pb = part + (((long)(t & 1) * NGRP + g) * NCOLB) * 640;
            if (localOK) inv_l1();               // partials re-use addresses (t-2)
            for (int task = tid; task < 640; task += 512) {
                float s = b2v[task % 5];
                if (localOK) {
#pragma unroll
                    for (int cc = 0; cc < NCOLB; ++cc) s += pb[cc * 640 + task];
                } else {
#pragma unroll
                    for (int cc = 0; cc < NCOLB; ++cc) s += coh_loadf(pb + cc * 640 + task);
                }
                out[(long)t * (NB * 5) + (long)g * 640 + task] = s;
            }

            __syncthreads();                     // all reads of part[t&1] done
            if (tid == 0)
                __hip_atomic_store(pBase + t, 1u,
                                   __ATOMIC_RELEASE, __HIP_MEMORY_SCOPE_AGENT);
        }
    }
}

// ---------------- launcher ----------------
extern "C" void kernel_launch(void* const* d_in, const int* in_sizes, int n_in,
                              void* d_out, int out_size, void* d_ws, size_t ws_size,
                              hipStream_t stream) {
    const int* ids   = (const int*)d_in[0];
    const float* emb = (const float*)d_in[1];
    const float* W   = (const float*)d_in[2];
    const float* bl  = (const float*)d_in[3];
    const float* U   = (const float*)d_in[4];
    const float* b2  = (const float*)d_in[5];
    float* out = (float*)d_out;

    // ws layout (16B-aligned, ~18.9 MB):
    //   WpT   0         ..   983,040   (4*320*384*2)
    //   H0    983,040   .. 1,638,400   (1024*320*2)
    //   H1    1,638,400 .. 2,293,760
    //   flgG  2,293,760 .. 2,370,560   (8*120*20*4)
    //   flgP  2,370,560 .. 2,374,400   (8*120*4)
    //   xcdA  2,374,400 .. 2,375,040   (160*4)
    //   part  2,375,040 .. 3,153,280   (2*8*19*640*4)
    //   Xp    3,153,280 .. 18,881,920  (120*1024*64*2)
    char* ws = (char*)d_ws;
    bf16_t*   WpT  = (bf16_t*)ws;
    bf16_t*   H0   = (bf16_t*)(ws + 983040);
    bf16_t*   H1   = (bf16_t*)(ws + 1638400);
    unsigned* flgG = (unsigned*)(ws + 2293760);
    unsigned* flgP = (unsigned*)(ws + 2370560);
    unsigned* xcdA = (unsigned*)(ws + 2374400);
    float*    part = (float*)(ws + 2375040);
    bf16_t*   Xp   = (bf16_t*)(ws + 3153280);

    prep_w<<<(4 * HP * KT + 255) / 256, 256, 0, stream>>>(W, WpT);
    // zero H0, H1, flgG, flgP, xcdA (contiguous 1,392,000 B = 87,000 uint4)
    prep_zero<<<(87000 + 255) / 256, 256, 0, stream>>>((uint4*)(ws + 983040), 87000);
    prep_x<<<(NB * NT * 4 + 255) / 256, 256, 0, stream>>>(ids, emb, Xp);

    void* kargs[] = { (void*)&bl, (void*)&WpT, (void*)&H0, (void*)&H1, (void*)&Xp,
                      (void*)&flgG, (void*)&flgP, (void*)&part, (void*)&xcdA,
                      (void*)&U, (void*)&b2, (void*)&out };
    hipError_t err = hipLaunchCooperativeKernel((const void*)lstm_persist,
                                                dim3(GRID), dim3(512), kargs, 0, stream);
    if (err != hipSuccess) {
        // co-residency holds anyway: 160 blocks <= 256 CUs, 50.2 KB LDS
        lstm_persist<<<GRID, 512, 0, stream>>>(bl, WpT, H0, H1, Xp,
                                               flgG, flgP, part, xcdA, U, b2, out);
    }
}

// Round 6
// 804.911 us; speedup vs baseline: 3.6929x; 1.5112x over previous
//
#include <hip/hip_runtime.h>
#include <hip/hip_bf16.h>

// Problem constants
#define NB 1024      // batch
#define NT 120       // seq len
#define NE 50        // embed
#define NH 300       // hidden
#define KX 64        // padded x K (50 -> 64): k-chunks 0..1
#define KH 320       // padded h K (300 -> 320): k-chunks 2..11
#define KT 384       // total padded K (12 chunks of 32)
#define HP 320       // padded h-cols per gate in WpT
#define NGRP 8       // row groups of 128 rows; group = blk & 7 (XCD-aligned)
#define NCOLB 19     // GEMM workers per group (19*16 = 304 >= 300 hidden cols)
#define ROLES 20     // 19 GEMM + 1 pred
#define GRID 160     // 8 groups * 20 roles; blk = role*8 + g
#define WCOL_STRIDE 784        // LDS W col stride: 768B data + 16B pad

typedef __bf16 bf16_t;
typedef __bf16 bf16x8 __attribute__((ext_vector_type(8)));
typedef float f32x4 __attribute__((ext_vector_type(4)));

// Fast, saturation-safe gates (error ~1e-6, negligible vs bf16-h rounding):
__device__ __forceinline__ float fsig(float x)  { return 1.0f / (1.0f + __expf(-x)); }
__device__ __forceinline__ float ftanh(float x) { return 2.0f / (1.0f + __expf(-2.0f * x)) - 1.0f; }

// ---- fallback (cross-XCD) transport: relaxed agent atomics (sc-bit, MALL) ----
__device__ __forceinline__ bf16x8 coh_load8(const bf16_t* p) {
    const unsigned long long* q = (const unsigned long long*)p;
    union { unsigned long long u[2]; bf16x8 v; } t;
    t.u[0] = __hip_atomic_load(q,     __ATOMIC_RELAXED, __HIP_MEMORY_SCOPE_AGENT);
    t.u[1] = __hip_atomic_load(q + 1, __ATOMIC_RELAXED, __HIP_MEMORY_SCOPE_AGENT);
    return t.v;
}
__device__ __forceinline__ void coh_store16(bf16_t* p, bf16_t h) {
    __hip_atomic_store((unsigned short*)p, __builtin_bit_cast(unsigned short, h),
                       __ATOMIC_RELAXED, __HIP_MEMORY_SCOPE_AGENT);
}
__device__ __forceinline__ void coh_storef(float* p, float v) {
    __hip_atomic_store((unsigned*)p, __builtin_bit_cast(unsigned, v),
                       __ATOMIC_RELAXED, __HIP_MEMORY_SCOPE_AGENT);
}
__device__ __forceinline__ float coh_loadf(const float* p) {
    unsigned u = __hip_atomic_load((const unsigned*)p,
                                   __ATOMIC_RELAXED, __HIP_MEMORY_SCOPE_AGENT);
    return __builtin_bit_cast(float, u);
}

// ---- local (same-XCD) transport helpers ----
// CU-local vector-L1 invalidate (sc0): subsequent plain loads are served by the
// XCD's L2, which producer write-through stores have reached (drained by the
// pre-flag __syncthreads vmcnt(0)). Trailing waitcnt: the inv completes before
// any following load issues.
__device__ __forceinline__ void inv_l1() {
    asm volatile("buffer_inv sc0\n\ts_waitcnt vmcnt(0)" ::: "memory");
}
// XCD id (HW_REG_XCC_ID, gfx940+; verified working on MI355X in round 5).
__device__ __forceinline__ unsigned xcc_id() {
    unsigned x;
    asm volatile("s_getreg_b32 %0, hwreg(HW_REG_XCC_ID)" : "=s"(x));
    return x & 0xfu;
}

// ---------------- prep kernels ----------------
__global__ void prep_w(const float* __restrict__ W, bf16_t* __restrict__ WpT) {
    int gid = blockIdx.x * 256 + threadIdx.x;
    if (gid >= 4 * HP * KT) return;
    int k = gid % KT;
    int col = gid / KT;
    int g = col / HP, hc = col % HP;
    int kp = -1;
    if (k < 50) kp = k;
    else if (k >= 64 && k < 364) kp = k - 14;
    float v = 0.0f;
    if (kp >= 0 && hc < NH) v = W[(long)kp * 1200 + g * NH + hc];
    WpT[gid] = (bf16_t)v;
}

__global__ void prep_zero(uint4* __restrict__ p, int n) {
    int gid = blockIdx.x * 256 + threadIdx.x;
    if (gid < n) p[gid] = make_uint4(0u, 0u, 0u, 0u);
}

// Pre-gather embeddings: Xp[t][b][0..63] bf16 (padded 50->64).
__global__ void prep_x(const int* __restrict__ ids, const float* __restrict__ emb,
                       bf16_t* __restrict__ Xp) {
    int gid = blockIdx.x * 256 + threadIdx.x;   // (b*NT + t)*4 + s
    if (gid >= NB * NT * 4) return;
    int s = gid & 3;
    int bt = gid >> 2;
    int b = bt / NT, t = bt % NT;
    int id = ids[bt];
    const float* er = emb + (long)id * NE;
    bf16_t* dst = Xp + ((long)t * NB + b) * KX + s * 16;
#pragma unroll
    for (int j = 0; j < 16; ++j) {
        int e = s * 16 + j;
        dst[j] = (bf16_t)((e < NE) ? er[e] : 0.0f);
    }
}

// ---------------- persistent LSTM kernel ----------------
// blk = role*8 + g. Roles 0..18: GEMM worker for hidden cols role*16..+15
// (all 4 gates) of group g (batch rows g*128..+127). Role 19: pred block.
// h/partials move through the group's XCD L2 when all 20 blocks share an XCD
// (runtime-verified), else through MALL agent atomics. Flags: relaxed agent
// atomics (NO release -> no buffer_wbl2 on the critical path; ordering comes
// from the pre-flag __syncthreads vmcnt(0) drain).
__global__ void __launch_bounds__(512, 2) lstm_persist(
    const float* __restrict__ bl, const bf16_t* __restrict__ WpT,
    bf16_t* H0, bf16_t* H1,
    const bf16_t* __restrict__ Xp,
    unsigned* flgG, unsigned* flgP, float* part, unsigned* xcdA,
    const float* __restrict__ U, const float* __restrict__ b2,
    float* __restrict__ out)
{
    __shared__ __align__(16) unsigned char smem[64 * WCOL_STRIDE];   // 50176 B
    __shared__ int sLocalOK;
    const int blk = blockIdx.x;
    const int tid = threadIdx.x;
    const int g = blk & 7;
    const int c = blk >> 3;                      // role
    const int lane = tid & 63, wave = tid >> 6;

    // ---- publish my XCD; verify all 20 group members share it
    if (tid == 0)
        __hip_atomic_store(xcdA + blk, xcc_id() + 1u,
                           __ATOMIC_RELAXED, __HIP_MEMORY_SCOPE_AGENT);
    if (wave == 0) {
        unsigned v = 1u;
        for (;;) {
            if (lane < ROLES)
                v = __hip_atomic_load(xcdA + (lane * NGRP + g), __ATOMIC_RELAXED,
                                      __HIP_MEMORY_SCOPE_AGENT);
            if (__all(v != 0)) break;
            __builtin_amdgcn_s_sleep(1);
        }
        unsigned ref = __shfl(v, 0, 64);
        int ok = __all(lane >= ROLES || v == ref);
        if (lane == 0) sLocalOK = ok;
    }

    unsigned* gBase = flgG + (long)g * NT * ROLES;
    unsigned* pBase = flgP + (long)g * NT;

    if (c < NCOLB) {
        // ================= GEMM worker =================
        // stage W slice into LDS (once): 64 cols (gate*16+mm), stride 784B
        for (int ch = tid; ch < 64 * 48; ch += 512) {
            int col = ch / 48, pq = ch % 48;
            int gt = col >> 4, mm = col & 15;
            int hc = c * 16 + mm;
            const uint4* src = (const uint4*)(WpT + (long)(gt * HP + hc) * KT) + pq;
            *(uint4*)(smem + col * WCOL_STRIDE + pq * 16) = *src;
        }

        const int m = lane & 15, quad = lane >> 4;
        const int rbase = g * 128 + wave * 16;   // this wave: rows rbase..rbase+15
        const int rowA  = rbase + m;
        const int hcOut = c * 16 + m;
        const bool colOK = (hcOut < NH);

        float bias[4] = {0.f, 0.f, 0.f, 0.f};
        float Ur[5]   = {0.f, 0.f, 0.f, 0.f, 0.f};
        if (colOK) {
#pragma unroll
            for (int gt = 0; gt < 4; ++gt) bias[gt] = bl[gt * NH + hcOut];
#pragma unroll
            for (int cc = 0; cc < 5; ++cc) Ur[cc] = U[hcOut * 5 + cc];
        }
        float cst[4] = {0.f, 0.f, 0.f, 0.f};

        __syncthreads();                         // W staged + sLocalOK visible
        const bool localOK = (sLocalOK != 0);

        // ---- hoist t-invariant B fragments (h-part kk=2..9, all gates) into
        // registers: 32 frags = 128 VGPRs. Cuts per-step LDS reads 48 -> 16.
        bf16x8 Bh[8][4];
#pragma unroll
        for (int kk = 0; kk < 8; ++kk)
#pragma unroll
            for (int gt = 0; gt < 4; ++gt)
                Bh[kk][gt] = *(const bf16x8*)(smem + (gt * 16 + m) * WCOL_STRIDE
                                              + ((kk + 2) * 4 + quad) * 16);

        for (int t = 0; t < NT; ++t) {
            // x fragments: plain cached loads (fresh addresses each t)
            const bf16x8* xv = (const bf16x8*)(Xp + ((long)t * NB + rowA) * KX);
            bf16x8 ax[2];
#pragma unroll
            for (int kk = 0; kk < 2; ++kk) ax[kk] = xv[kk * 4 + quad];

            f32x4 acc[4];
#pragma unroll
            for (int gt = 0; gt < 4; ++gt) acc[gt] = (f32x4){0.f, 0.f, 0.f, 0.f};

            // x-part MFMAs BEFORE the wait (no h dependency): k-chunks 0..1
#pragma unroll
            for (int kk = 0; kk < 2; ++kk) {
#pragma unroll
                for (int gt = 0; gt < 4; ++gt) {
                    bf16x8 b = *(const bf16x8*)(smem + (gt * 16 + m) * WCOL_STRIDE
                                                + (kk * 4 + quad) * 16);
                    acc[gt] = __builtin_amdgcn_mfma_f32_16x16x32_bf16(ax[kk], b, acc[gt], 0, 0, 0);
                }
            }

            // wait: 19 sibling h-flags of t-1; pred done with partials (t-2)
            if (t > 0) {
                if (wave == 0) {
                    const unsigned* gf = gBase + (long)(t - 1) * ROLES;
                    const unsigned* pf = pBase + (t - 2);
                    const bool needP = (t >= 2);
                    for (;;) {
                        unsigned v = 1u;
                        if (lane < NCOLB)
                            v = __hip_atomic_load(gf + lane, __ATOMIC_RELAXED,
                                                  __HIP_MEMORY_SCOPE_AGENT);
                        else if (lane == NCOLB && needP)
                            v = __hip_atomic_load(pf, __ATOMIC_RELAXED,
                                                  __HIP_MEMORY_SCOPE_AGENT);
                        if (__all(v != 0)) break;
                        __builtin_amdgcn_s_sleep(1);
                    }
                }
            }
            __syncthreads();
            __builtin_amdgcn_sched_barrier(0);

            const bf16_t* Hr = (t & 1) ? H1 : H0;
            bf16_t*       Hw = (t & 1) ? H0 : H1;

            // ---- h A-fragments
            const bf16_t* hp = Hr + (long)rowA * KH;
            bf16x8 ah[10];
            if (localOK) {
                inv_l1();                        // L1 may hold stale h (t-2)
                const bf16x8* hv = (const bf16x8*)hp;
#pragma unroll
                for (int i = 0; i < 10; ++i) ah[i] = hv[i * 4 + quad];
            } else {
#pragma unroll
                for (int i = 0; i < 10; ++i) ah[i] = coh_load8(hp + (i * 4 + quad) * 8);
            }
            __builtin_amdgcn_sched_barrier(0);

            // h part: k-chunks 2..9 from registers, 10..11 from LDS
#pragma unroll
            for (int kk = 2; kk < 10; ++kk) {
#pragma unroll
                for (int gt = 0; gt < 4; ++gt)
                    acc[gt] = __builtin_amdgcn_mfma_f32_16x16x32_bf16(
                        ah[kk - 2], Bh[kk - 2][gt], acc[gt], 0, 0, 0);
            }
#pragma unroll
            for (int kk = 10; kk < 12; ++kk) {
#pragma unroll
                for (int gt = 0; gt < 4; ++gt) {
                    bf16x8 b = *(const bf16x8*)(smem + (gt * 16 + m) * WCOL_STRIDE
                                                + (kk * 4 + quad) * 16);
                    acc[gt] = __builtin_amdgcn_mfma_f32_16x16x32_bf16(ah[kk - 2], b, acc[gt], 0, 0, 0);
                }
            }

            // ---- gates + state update (C/D: col = lane&15, row = quad*4 + r)
            float hn_[4];
#pragma unroll
            for (int r = 0; r < 4; ++r) {
                float zi = acc[0][r] + bias[0];
                float zj = acc[1][r] + bias[1];
                float zf = acc[2][r] + bias[2];
                float zo = acc[3][r] + bias[3];
                float cn = cst[r] * fsig(zf + 1.0f) + fsig(zi) * ftanh(zj);
                cst[r] = cn;
                hn_[r] = ftanh(cn) * fsig(zo);
            }
            if (colOK) {
                if (localOK) {
#pragma unroll
                    for (int r = 0; r < 4; ++r)
                        Hw[(long)(rbase + quad * 4 + r) * KH + hcOut] = (bf16_t)hn_[r];
                } else {
#pragma unroll
                    for (int r = 0; r < 4; ++r)
                        coh_store16(Hw + (long)(rbase + quad * 4 + r) * KH + hcOut,
                                    (bf16_t)hn_[r]);
                }
            }

            // ---- fold this block's 16-col pred contribution -> partials
            {
                float p[4][5];
#pragma unroll
                for (int r = 0; r < 4; ++r)
#pragma unroll
                    for (int cc = 0; cc < 5; ++cc) p[r][cc] = hn_[r] * Ur[cc];
#pragma unroll
                for (int k = 1; k < 16; k <<= 1) {
#pragma unroll
                    for (int r = 0; r < 4; ++r)
#pragma unroll
                        for (int cc = 0; cc < 5; ++cc)
                            p[r][cc] += __shfl_xor(p[r][cc], k, 16);
                }
                if (m == 0) {
                    float* pb = part + (((long)(t & 1) * NGRP + g) * NCOLB + c) * 640;
#pragma unroll
                    for (int r = 0; r < 4; ++r) {
                        int rl = wave * 16 + quad * 4 + r;
                        if (localOK) {
#pragma unroll
                            for (int cc = 0; cc < 5; ++cc) pb[rl * 5 + cc] = p[r][cc];
                        } else {
#pragma unroll
                            for (int cc = 0; cc < 5; ++cc) coh_storef(pb + rl * 5 + cc, p[r][cc]);
                        }
                    }
                }
            }

            __syncthreads();   // all waves' h + partial stores drained (vmcnt 0)
            if (tid == 0)
                __hip_atomic_store(gBase + (long)t * ROLES + c, 1u,
                                   __ATOMIC_RELAXED, __HIP_MEMORY_SCOPE_AGENT);
        }
    } else {
        // ================= pred block: out[t] = sum_c partials + b2 =================
        float b2v[5];
#pragma unroll
        for (int cc = 0; cc < 5; ++cc) b2v[cc] = b2[cc];
        __syncthreads();
        const bool localOK = (sLocalOK != 0);

        for (int t = 0; t < NT; ++t) {
            if (wave == 0) {
                const unsigned* gf = gBase + (long)t * ROLES;
                for (;;) {
                    unsigned v = 1u;
                    if (lane < NCOLB)
                        v = __hip_atomic_load(gf + lane, __ATOMIC_RELAXED,
                                              __HIP_MEMORY_SCOPE_AGENT);
                    if (__all(v != 0)) break;
                    __builtin_amdgcn_s_sleep(1);
                }
            }
            __syncthreads();
            __builtin_amdgcn_sched_barrier(0);

            const float* pb = part + (((long)(t & 1) * NGRP + g) * NCOLB) * 640;
            if (localOK) inv_l1();               // partials re-use addresses (t-2)
            for (int task = tid; task < 640; task += 512) {
                float s = b2v[task % 5];
                if (localOK) {
#pragma unroll
                    for (int cc = 0; cc < NCOLB; ++cc) s += pb[cc * 640 + task];
                } else {
#pragma unroll
                    for (int cc = 0; cc < NCOLB; ++cc) s += coh_loadf(pb + cc * 640 + task);
                }
                out[(long)t * (NB * 5) + (long)g * 640 + task] = s;
            }

            __syncthreads();                     // all reads of part[t&1] done
            if (tid == 0)
                __hip_atomic_store(pBase + t, 1u,
                                   __ATOMIC_RELAXED, __HIP_MEMORY_SCOPE_AGENT);
        }
    }
}

// ---------------- launcher ----------------
extern "C" void kernel_launch(void* const* d_in, const int* in_sizes, int n_in,
                              void* d_out, int out_size, void* d_ws, size_t ws_size,
                              hipStream_t stream) {
    const int* ids   = (const int*)d_in[0];
    const float* emb = (const float*)d_in[1];
    const float* W   = (const float*)d_in[2];
    const float* bl  = (const float*)d_in[3];
    const float* U   = (const float*)d_in[4];
    const float* b2  = (const float*)d_in[5];
    float* out = (float*)d_out;

    // ws layout (16B-aligned, ~18.9 MB):
    //   WpT   0         ..   983,040   (4*320*384*2)
    //   H0    983,040   .. 1,638,400   (1024*320*2)
    //   H1    1,638,400 .. 2,293,760
    //   flgG  2,293,760 .. 2,370,560   (8*120*20*4)
    //   flgP  2,370,560 .. 2,374,400   (8*120*4)
    //   xcdA  2,374,400 .. 2,375,040   (160*4)
    //   part  2,375,040 .. 3,153,280   (2*8*19*640*4)
    //   Xp    3,153,280 .. 18,881,920  (120*1024*64*2)
    char* ws = (char*)d_ws;
    bf16_t*   WpT  = (bf16_t*)ws;
    bf16_t*   H0   = (bf16_t*)(ws + 983040);
    bf16_t*   H1   = (bf16_t*)(ws + 1638400);
    unsigned* flgG = (unsigned*)(ws + 2293760);
    unsigned* flgP = (unsigned*)(ws + 2370560);
    unsigned* xcdA = (unsigned*)(ws + 2374400);
    float*    part = (float*)(ws + 2375040);
    bf16_t*   Xp   = (bf16_t*)(ws + 3153280);

    prep_w<<<(4 * HP * KT + 255) / 256, 256, 0, stream>>>(W, WpT);
    // zero H0, H1, flgG, flgP, xcdA (contiguous 1,392,000 B = 87,000 uint4)
    prep_zero<<<(87000 + 255) / 256, 256, 0, stream>>>((uint4*)(ws + 983040), 87000);
    prep_x<<<(NB * NT * 4 + 255) / 256, 256, 0, stream>>>(ids, emb, Xp);

    void* kargs[] = { (void*)&bl, (void*)&WpT, (void*)&H0, (void*)&H1, (void*)&Xp,
                      (void*)&flgG, (void*)&flgP, (void*)&part, (void*)&xcdA,
                      (void*)&U, (void*)&b2, (void*)&out };
    hipError_t err = hipLaunchCooperativeKernel((const void*)lstm_persist,
                                                dim3(GRID), dim3(512), kargs, 0, stream);
    if (err != hipSuccess) {
        // co-residency holds anyway: 160 blocks <= 256 CUs, 50.2 KB LDS
        lstm_persist<<<GRID, 512, 0, stream>>>(bl, WpT, H0, H1, Xp,
                                               flgG, flgP, part, xcdA, U, b2, out);
    }
}

// Round 9
// 802.279 us; speedup vs baseline: 3.7050x; 1.0033x over previous
//
#include <hip/hip_runtime.h>
#include <hip/hip_bf16.h>

// ROUND 9: r7 intent (L2-local flags, PSLOTS=4, fused prep) rebuilt on
// r5/r6-proven primitives only. r7/r8's sc0-load flag poll could legally hit
// stale L1 -> infinite spin (likely cause of the container failures). Local
// flag transport is now: publish = plain volatile store (== proven h-store
// path); poll = inv_l1() + plain volatile load (== proven h-read path).

// Problem constants
#define NB 1024      // batch
#define NT 120       // seq len
#define NE 50        // embed
#define NH 300       // hidden
#define KX 64        // padded x K (50 -> 64): k-chunks 0..1
#define KH 320       // padded h K (300 -> 320): k-chunks 2..11
#define KT 384       // total padded K (12 chunks of 32)
#define HP 320       // padded h-cols per gate in WpT
#define NGRP 8       // row groups of 128 rows; group = blk & 7 (XCD-aligned)
#define NCOLB 19     // GEMM workers per group (19*16 = 304 >= 300 hidden cols)
#define ROLES 20     // 19 GEMM + 1 pred
#define GRID 160     // 8 groups * 20 roles; blk = role*8 + g
#define WCOL_STRIDE 784        // LDS W col stride: 768B data + 16B pad
#define PSLOTS 4     // pred partial buffers; GEMM gates on pflag(t-4)

typedef __bf16 bf16_t;
typedef __bf16 bf16x8 __attribute__((ext_vector_type(8)));
typedef float f32x4 __attribute__((ext_vector_type(4)));

// Fast, saturation-safe gates (error ~1e-6, negligible vs bf16-h rounding):
__device__ __forceinline__ float fsig(float x)  { return 1.0f / (1.0f + __expf(-x)); }
__device__ __forceinline__ float ftanh(float x) { return 2.0f / (1.0f + __expf(-2.0f * x)) - 1.0f; }

// ---- fallback (cross-XCD) transport: relaxed agent atomics (MALL) ----
__device__ __forceinline__ bf16x8 coh_load8(const bf16_t* p) {
    const unsigned long long* q = (const unsigned long long*)p;
    union { unsigned long long u[2]; bf16x8 v; } t;
    t.u[0] = __hip_atomic_load(q,     __ATOMIC_RELAXED, __HIP_MEMORY_SCOPE_AGENT);
    t.u[1] = __hip_atomic_load(q + 1, __ATOMIC_RELAXED, __HIP_MEMORY_SCOPE_AGENT);
    return t.v;
}
__device__ __forceinline__ void coh_store16(bf16_t* p, bf16_t h) {
    __hip_atomic_store((unsigned short*)p, __builtin_bit_cast(unsigned short, h),
                       __ATOMIC_RELAXED, __HIP_MEMORY_SCOPE_AGENT);
}
__device__ __forceinline__ void coh_storef(float* p, float v) {
    __hip_atomic_store((unsigned*)p, __builtin_bit_cast(unsigned, v),
                       __ATOMIC_RELAXED, __HIP_MEMORY_SCOPE_AGENT);
}
__device__ __forceinline__ float coh_loadf(const float* p) {
    unsigned u = __hip_atomic_load((const unsigned*)p,
                                   __ATOMIC_RELAXED, __HIP_MEMORY_SCOPE_AGENT);
    return __builtin_bit_cast(float, u);
}
__device__ __forceinline__ unsigned coh_loadu(const unsigned* p) {
    return __hip_atomic_load(p, __ATOMIC_RELAXED, __HIP_MEMORY_SCOPE_AGENT);
}

// ---- local (same-XCD) transport helpers ----
// CU-local vector-L1 invalidate; following plain loads are L2-served.
// PROVEN on this chip: r5/r6 used exactly this sequence before every h read,
// with numerically correct results (stale h would have failed the check).
__device__ __forceinline__ void inv_l1() {
    asm volatile("buffer_inv sc0\n\ts_waitcnt vmcnt(0)" ::: "memory");
}
// XCD id (HW_REG_XCC_ID; verified working on MI355X in round 5).
__device__ __forceinline__ unsigned xcc_id() {
    unsigned x;
    asm volatile("s_getreg_b32 %0, hwreg(HW_REG_XCC_ID)" : "=s"(x));
    return x & 0xfu;
}

// ---------------- fused prep kernel (one launch) ----------------
// Tasks (independent buffers, grid-stride): zero H0/H1/flags/xcdA; pack W->WpT;
// gather embeddings -> Xp[t][b][0..63].
__global__ void prep_all(const int* __restrict__ ids, const float* __restrict__ emb,
                         const float* __restrict__ W,
                         bf16_t* __restrict__ WpT, uint4* __restrict__ zbase,
                         int nzero, bf16_t* __restrict__ Xp) {
    const long stride = (long)gridDim.x * 256;
    const long g0 = (long)blockIdx.x * 256 + threadIdx.x;

    for (long i = g0; i < nzero; i += stride)
        zbase[i] = make_uint4(0u, 0u, 0u, 0u);

    for (long gid = g0; gid < 4 * HP * KT; gid += stride) {
        int k = (int)(gid % KT);
        int col = (int)(gid / KT);
        int g = col / HP, hc = col % HP;
        int kp = -1;
        if (k < 50) kp = k;
        else if (k >= 64 && k < 364) kp = k - 14;
        float v = 0.0f;
        if (kp >= 0 && hc < NH) v = W[(long)kp * 1200 + g * NH + hc];
        WpT[gid] = (bf16_t)v;
    }

    for (long gid = g0; gid < (long)NB * NT * 4; gid += stride) {
        int s = (int)(gid & 3);
        long bt = gid >> 2;
        int b = (int)(bt / NT), t = (int)(bt % NT);
        int id = ids[bt];
        const float* er = emb + (long)id * NE;
        bf16_t* dst = Xp + ((long)t * NB + b) * KX + s * 16;
#pragma unroll
        for (int j = 0; j < 16; ++j) {
            int e = s * 16 + j;
            dst[j] = (bf16_t)((e < NE) ? er[e] : 0.0f);
        }
    }
}

// ---------------- persistent LSTM kernel ----------------
// blk = role*8 + g. Roles 0..18: GEMM worker for hidden cols role*16..+15
// (all 4 gates) of group g (batch rows g*128..+127). Role 19: pred block.
// When all 20 blocks of a group share an XCD (runtime-verified), h, partials
// AND flags move through that XCD's L2 (plain write-through stores; inv_l1 +
// plain loads). Else: MALL agent atomics (correct anywhere).
__global__ void __launch_bounds__(512, 2) lstm_persist(
    const float* __restrict__ bl, const bf16_t* __restrict__ WpT,
    bf16_t* H0, bf16_t* H1,
    const bf16_t* __restrict__ Xp,
    unsigned* flgG, unsigned* flgP, float* part, unsigned* xcdA,
    const float* __restrict__ U, const float* __restrict__ b2,
    float* __restrict__ out)
{
    __shared__ __align__(16) unsigned char smem[64 * WCOL_STRIDE];   // 50176 B
    __shared__ int sLocalOK;
    const int blk = blockIdx.x;
    const int tid = threadIdx.x;
    const int g = blk & 7;
    const int c = blk >> 3;                      // role
    const int lane = tid & 63, wave = tid >> 6;

    // ---- publish my XCD; verify all 20 group members share it
    if (tid == 0)
        __hip_atomic_store(xcdA + blk, xcc_id() + 1u,
                           __ATOMIC_RELAXED, __HIP_MEMORY_SCOPE_AGENT);
    if (wave == 0) {
        unsigned v = 1u;
        for (;;) {
            if (lane < ROLES)
                v = coh_loadu(xcdA + (lane * NGRP + g));
            if (__all(v != 0)) break;
            __builtin_amdgcn_s_sleep(1);
        }
        unsigned ref = __shfl(v, 0, 64);
        int ok = __all(lane >= ROLES || v == ref);
        if (lane == 0) sLocalOK = ok;
    }

    unsigned* gBase = flgG + (long)g * NT * ROLES;
    unsigned* pBase = flgP + (long)g * NT;

    if (c < NCOLB) {
        // ================= GEMM worker =================
        // stage W slice into LDS (once): 64 cols (gate*16+mm), stride 784B
        for (int ch = tid; ch < 64 * 48; ch += 512) {
            int col = ch / 48, pq = ch % 48;
            int gt = col >> 4, mm = col & 15;
            int hc = c * 16 + mm;
            const uint4* src = (const uint4*)(WpT + (long)(gt * HP + hc) * KT) + pq;
            *(uint4*)(smem + col * WCOL_STRIDE + pq * 16) = *src;
        }

        const int m = lane & 15, quad = lane >> 4;
        const int rbase = g * 128 + wave * 16;   // this wave: rows rbase..rbase+15
        const int rowA  = rbase + m;
        const int hcOut = c * 16 + m;
        const bool colOK = (hcOut < NH);

        float bias[4] = {0.f, 0.f, 0.f, 0.f};
        float Ur[5]   = {0.f, 0.f, 0.f, 0.f, 0.f};
        if (colOK) {
#pragma unroll
            for (int gt = 0; gt < 4; ++gt) bias[gt] = bl[gt * NH + hcOut];
#pragma unroll
            for (int cc = 0; cc < 5; ++cc) Ur[cc] = U[hcOut * 5 + cc];
        }
        float cst[4] = {0.f, 0.f, 0.f, 0.f};

        __syncthreads();                         // W staged + sLocalOK visible
        const bool localOK = (sLocalOK != 0);

        // ---- hoist t-invariant B fragments (h-part kk=2..9, all gates) into
        // registers; cuts per-step LDS reads 48 -> 16.
        bf16x8 Bh[8][4];
#pragma unroll
        for (int kk = 0; kk < 8; ++kk)
#pragma unroll
            for (int gt = 0; gt < 4; ++gt)
                Bh[kk][gt] = *(const bf16x8*)(smem + (gt * 16 + m) * WCOL_STRIDE
                                              + ((kk + 2) * 4 + quad) * 16);

        for (int t = 0; t < NT; ++t) {
            // x fragments: plain cached loads (fresh addresses each t)
            const bf16x8* xv = (const bf16x8*)(Xp + ((long)t * NB + rowA) * KX);
            bf16x8 ax[2];
#pragma unroll
            for (int kk = 0; kk < 2; ++kk) ax[kk] = xv[kk * 4 + quad];

            f32x4 acc[4];
#pragma unroll
            for (int gt = 0; gt < 4; ++gt) acc[gt] = (f32x4){0.f, 0.f, 0.f, 0.f};

            // x-part MFMAs BEFORE the wait (no h dependency): k-chunks 0..1
#pragma unroll
            for (int kk = 0; kk < 2; ++kk) {
#pragma unroll
                for (int gt = 0; gt < 4; ++gt) {
                    bf16x8 b = *(const bf16x8*)(smem + (gt * 16 + m) * WCOL_STRIDE
                                                + (kk * 4 + quad) * 16);
                    acc[gt] = __builtin_amdgcn_mfma_f32_16x16x32_bf16(ax[kk], b, acc[gt], 0, 0, 0);
                }
            }

            // wait: 19 sibling h-flags of t-1; pred done with partials (t-4)
            if (t > 0) {
                if (wave == 0) {
                    const unsigned* gf = gBase + (long)(t - 1) * ROLES;
                    const bool needP = (t >= PSLOTS);
                    const unsigned* ap = (lane < NCOLB) ? (gf + lane)
                                                        : (pBase + (t - PSLOTS));
                    const bool active = (lane < NCOLB) || (lane == NCOLB && needP);
                    if (localOK) {
                        for (;;) {
                            inv_l1();            // fresh L2 view each iteration
                            unsigned v = active ? *(const volatile unsigned*)ap : 1u;
                            if (__all(v != 0)) break;
                            __builtin_amdgcn_s_sleep(1);
                        }
                    } else {
                        for (;;) {
                            unsigned v = active ? coh_loadu(ap) : 1u;
                            if (__all(v != 0)) break;
                            __builtin_amdgcn_s_sleep(1);
                        }
                    }
                }
            }
            __syncthreads();
            __builtin_amdgcn_sched_barrier(0);

            const bf16_t* Hr = (t & 1) ? H1 : H0;
            bf16_t*       Hw = (t & 1) ? H0 : H1;

            // ---- h A-fragments
            const bf16_t* hp = Hr + (long)rowA * KH;
            bf16x8 ah[10];
            if (localOK) {
                inv_l1();                        // L1 may hold stale h (t-2)
                const bf16x8* hv = (const bf16x8*)hp;
#pragma unroll
                for (int i = 0; i < 10; ++i) ah[i] = hv[i * 4 + quad];
            } else {
#pragma unroll
                for (int i = 0; i < 10; ++i) ah[i] = coh_load8(hp + (i * 4 + quad) * 8);
            }
            __builtin_amdgcn_sched_barrier(0);

            // h part: k-chunks 2..9 from registers, 10..11 from LDS
#pragma unroll
            for (int kk = 2; kk < 10; ++kk) {
#pragma unroll
                for (int gt = 0; gt < 4; ++gt)
                    acc[gt] = __builtin_amdgcn_mfma_f32_16x16x32_bf16(
                        ah[kk - 2], Bh[kk - 2][gt], acc[gt], 0, 0, 0);
            }
#pragma unroll
            for (int kk = 10; kk < 12; ++kk) {
#pragma unroll
                for (int gt = 0; gt < 4; ++gt) {
                    bf16x8 b = *(const bf16x8*)(smem + (gt * 16 + m) * WCOL_STRIDE
                                                + (kk * 4 + quad) * 16);
                    acc[gt] = __builtin_amdgcn_mfma_f32_16x16x32_bf16(ah[kk - 2], b, acc[gt], 0, 0, 0);
                }
            }

            // ---- gates + state update (C/D: col = lane&15, row = quad*4 + r)
            float hn_[4];
#pragma unroll
            for (int r = 0; r < 4; ++r) {
                float zi = acc[0][r] + bias[0];
                float zj = acc[1][r] + bias[1];
                float zf = acc[2][r] + bias[2];
                float zo = acc[3][r] + bias[3];
                float cn = cst[r] * fsig(zf + 1.0f) + fsig(zi) * ftanh(zj);
                cst[r] = cn;
                hn_[r] = ftanh(cn) * fsig(zo);
            }
            if (colOK) {
                if (localOK) {
#pragma unroll
                    for (int r = 0; r < 4; ++r)
                        Hw[(long)(rbase + quad * 4 + r) * KH + hcOut] = (bf16_t)hn_[r];
                } else {
#pragma unroll
                    for (int r = 0; r < 4; ++r)
                        coh_store16(Hw + (long)(rbase + quad * 4 + r) * KH + hcOut,
                                    (bf16_t)hn_[r]);
                }
            }

            // ---- fold this block's 16-col pred contribution -> partials
            {
                float p[4][5];
#pragma unroll
                for (int r = 0; r < 4; ++r)
#pragma unroll
                    for (int cc = 0; cc < 5; ++cc) p[r][cc] = hn_[r] * Ur[cc];
#pragma unroll
                for (int k = 1; k < 16; k <<= 1) {
#pragma unroll
                    for (int r = 0; r < 4; ++r)
#pragma unroll
                        for (int cc = 0; cc < 5; ++cc)
                            p[r][cc] += __shfl_xor(p[r][cc], k, 16);
                }
                if (m == 0) {
                    float* pb = part + (((long)(t & (PSLOTS - 1)) * NGRP + g) * NCOLB + c) * 640;
#pragma unroll
                    for (int r = 0; r < 4; ++r) {
                        int rl = wave * 16 + quad * 4 + r;
                        if (localOK) {
#pragma unroll
                            for (int cc = 0; cc < 5; ++cc) pb[rl * 5 + cc] = p[r][cc];
                        } else {
#pragma unroll
                            for (int cc = 0; cc < 5; ++cc) coh_storef(pb + rl * 5 + cc, p[r][cc]);
                        }
                    }
                }
            }

            __syncthreads();   // all waves' h + partial stores drained (vmcnt 0)
            if (tid == 0) {
                unsigned* fp = gBase + (long)t * ROLES + c;
                if (localOK) *(volatile unsigned*)fp = 1u;   // write-through -> L2
                else __hip_atomic_store(fp, 1u, __ATOMIC_RELAXED,
                                        __HIP_MEMORY_SCOPE_AGENT);
            }
        }
    } else {
        // ================= pred block: out[t] = sum_c partials + b2 =================
        float b2v[5];
#pragma unroll
        for (int cc = 0; cc < 5; ++cc) b2v[cc] = b2[cc];
        __syncthreads();
        const bool localOK = (sLocalOK != 0);

        for (int t = 0; t < NT; ++t) {
            if (wave == 0) {
                const unsigned* gf = gBase + (long)t * ROLES;
                if (localOK) {
                    for (;;) {
                        inv_l1();
                        unsigned v = (lane < NCOLB) ? *(const volatile unsigned*)(gf + lane) : 1u;
                        if (__all(v != 0)) break;
                        __builtin_amdgcn_s_sleep(1);
                    }
                } else {
                    for (;;) {
                        unsigned v = (lane < NCOLB) ? coh_loadu(gf + lane) : 1u;
                        if (__all(v != 0)) break;
                        __builtin_amdgcn_s_sleep(1);
                    }
                }
            }
            __syncthreads();
            __builtin_amdgcn_sched_barrier(0);

            const float* pb = part + (((long)(t & (PSLOTS - 1)) * NGRP + g) * NCOLB) * 640;
            if (localOK) inv_l1();               // partials re-use addresses (t-4)
            for (int task = tid; task < 640; task += 512) {
                float s = b2v[task % 5];
                if (localOK) {
#pragma unroll
                    for (int cc = 0; cc < NCOLB; ++cc) s += pb[cc * 640 + task];
                } else {
#pragma unroll
                    for (int cc = 0; cc < NCOLB; ++cc) s += coh_loadf(pb + cc * 640 + task);
                }
                out[(long)t * (NB * 5) + (long)g * 640 + task] = s;
            }

            __syncthreads();                     // all reads of part slot done
            if (tid == 0) {
                unsigned* fp = pBase + t;
                if (localOK) *(volatile unsigned*)fp = 1u;
                else __hip_atomic_store(fp, 1u, __ATOMIC_RELAXED,
                                        __HIP_MEMORY_SCOPE_AGENT);
            }
        }
    }
}

// ---------------- launcher ----------------
extern "C" void kernel_launch(void* const* d_in, const int* in_sizes, int n_in,
                              void* d_out, int out_size, void* d_ws, size_t ws_size,
                              hipStream_t stream) {
    const int* ids   = (const int*)d_in[0];
    const float* emb = (const float*)d_in[1];
    const float* W   = (const float*)d_in[2];
    const float* bl  = (const float*)d_in[3];
    const float* U   = (const float*)d_in[4];
    const float* b2  = (const float*)d_in[5];
    float* out = (float*)d_out;

    // ws layout (16B-aligned, ~19.7 MB):
    //   WpT   0         ..   983,040   (4*320*384*2)
    //   H0    983,040   .. 1,638,400   (1024*320*2)
    //   H1    1,638,400 .. 2,293,760
    //   flgG  2,293,760 .. 2,370,560   (8*120*20*4)
    //   flgP  2,370,560 .. 2,374,400   (8*120*4)
    //   xcdA  2,374,400 .. 2,375,040   (160*4)
    //   part  2,375,040 .. 3,931,520   (4*8*19*640*4)
    //   Xp    3,931,520 .. 19,660,160  (120*1024*64*2)
    char* ws = (char*)d_ws;
    bf16_t*   WpT  = (bf16_t*)ws;
    bf16_t*   H0   = (bf16_t*)(ws + 983040);
    bf16_t*   H1   = (bf16_t*)(ws + 1638400);
    unsigned* flgG = (unsigned*)(ws + 2293760);
    unsigned* flgP = (unsigned*)(ws + 2370560);
    unsigned* xcdA = (unsigned*)(ws + 2374400);
    float*    part = (float*)(ws + 2375040);
    bf16_t*   Xp   = (bf16_t*)(ws + 3931520);

    // one fused prep launch: zero H0/H1/flgG/flgP/xcdA (87,000 uint4), pack W,
    // gather embeddings
    prep_all<<<2048, 256, 0, stream>>>(ids, emb, W, WpT,
                                       (uint4*)(ws + 983040), 87000, Xp);

    void* kargs[] = { (void*)&bl, (void*)&WpT, (void*)&H0, (void*)&H1, (void*)&Xp,
                      (void*)&flgG, (void*)&flgP, (void*)&part, (void*)&xcdA,
                      (void*)&U, (void*)&b2, (void*)&out };
    hipError_t err = hipLaunchCooperativeKernel((const void*)lstm_persist,
                                                dim3(GRID), dim3(512), kargs, 0, stream);
    if (err != hipSuccess) {
        // co-residency holds anyway: 160 blocks <= 256 CUs, 50.2 KB LDS
        lstm_persist<<<GRID, 512, 0, stream>>>(bl, WpT, H0, H1, Xp,
                                               flgG, flgP, part, xcdA, U, b2, out);
    }
}

// Round 10
// 643.232 us; speedup vs baseline: 4.6211x; 1.2473x over previous
//
#include <hip/hip_runtime.h>
#include <hip/hip_bf16.h>

// ROUND 10: r9 post-mortem showed flag transport is NOT the bottleneck
// (r6 ~= r9). VGPR=112 proves Bh was rematerialized from LDS -> 384
// ds_read_b128/block/step (~1.9us). Fixes: (1) asm keep-alive forces Bh
// into VGPRs; (2) one L1-inv per step (poll-exit inv suffices); (3) rcp
// gates; (4) pred via MFMA w/ split-precision U (hi+lo bf16), H[4] ring,
// partials machinery deleted.

// Problem constants
#define NB 1024      // batch
#define NT 120       // seq len
#define NE 50        // embed
#define NH 300       // hidden
#define KX 64        // padded x K (50 -> 64): k-chunks 0..1
#define KH 320       // padded h K (300 -> 320): k-chunks 2..11
#define KT 384       // total padded K (12 chunks of 32)
#define HP 320       // padded h-cols per gate in WpT
#define NGRP 8       // row groups of 128 rows; group = blk & 7 (XCD-aligned)
#define NCOLB 19     // GEMM workers per group (19*16 = 304 >= 300 hidden cols)
#define ROLES 20     // 19 GEMM + 1 pred
#define GRID 160     // 8 groups * 20 roles; blk = role*8 + g
#define WCOL_STRIDE 784        // LDS W col stride: 768B data + 16B pad
#define HSLOTS 4     // h ring buffers; GEMM t writes slot t&3, gates pflag(t-4)

typedef __bf16 bf16_t;
typedef __bf16 bf16x8 __attribute__((ext_vector_type(8)));
typedef float f32x4 __attribute__((ext_vector_type(4)));

// Fast gates: v_rcp_f32 instead of full-precision divide (~1e-7 rel err,
// negligible vs bf16-h rounding). Saturation-safe: rcp(inf)=0.
__device__ __forceinline__ float fsig(float x) {
    return __builtin_amdgcn_rcpf(1.0f + __expf(-x));
}
__device__ __forceinline__ float ftanh(float x) {
    return fmaf(2.0f, __builtin_amdgcn_rcpf(1.0f + __expf(-2.0f * x)), -1.0f);
}

// ---- fallback (cross-XCD) transport: relaxed agent atomics (MALL) ----
__device__ __forceinline__ bf16x8 coh_load8(const bf16_t* p) {
    const unsigned long long* q = (const unsigned long long*)p;
    union { unsigned long long u[2]; bf16x8 v; } t;
    t.u[0] = __hip_atomic_load(q,     __ATOMIC_RELAXED, __HIP_MEMORY_SCOPE_AGENT);
    t.u[1] = __hip_atomic_load(q + 1, __ATOMIC_RELAXED, __HIP_MEMORY_SCOPE_AGENT);
    return t.v;
}
__device__ __forceinline__ void coh_store16(bf16_t* p, bf16_t h) {
    __hip_atomic_store((unsigned short*)p, __builtin_bit_cast(unsigned short, h),
                       __ATOMIC_RELAXED, __HIP_MEMORY_SCOPE_AGENT);
}
__device__ __forceinline__ unsigned coh_loadu(const unsigned* p) {
    return __hip_atomic_load(p, __ATOMIC_RELAXED, __HIP_MEMORY_SCOPE_AGENT);
}

// ---- local (same-XCD) transport helpers (proven r5/r6/r9) ----
__device__ __forceinline__ void inv_l1() {
    asm volatile("buffer_inv sc0\n\ts_waitcnt vmcnt(0)" ::: "memory");
}
__device__ __forceinline__ unsigned xcc_id() {
    unsigned x;
    asm volatile("s_getreg_b32 %0, hwreg(HW_REG_XCC_ID)" : "=s"(x));
    return x & 0xfu;
}

// ---------------- fused prep kernel (one launch) ----------------
__global__ void prep_all(const int* __restrict__ ids, const float* __restrict__ emb,
                         const float* __restrict__ W,
                         bf16_t* __restrict__ WpT, uint4* __restrict__ zbase,
                         int nzero, bf16_t* __restrict__ Xp) {
    const long stride = (long)gridDim.x * 256;
    const long g0 = (long)blockIdx.x * 256 + threadIdx.x;

    for (long i = g0; i < nzero; i += stride)
        zbase[i] = make_uint4(0u, 0u, 0u, 0u);

    for (long gid = g0; gid < 4 * HP * KT; gid += stride) {
        int k = (int)(gid % KT);
        int col = (int)(gid / KT);
        int g = col / HP, hc = col % HP;
        int kp = -1;
        if (k < 50) kp = k;
        else if (k >= 64 && k < 364) kp = k - 14;
        float v = 0.0f;
        if (kp >= 0 && hc < NH) v = W[(long)kp * 1200 + g * NH + hc];
        WpT[gid] = (bf16_t)v;
    }

    for (long gid = g0; gid < (long)NB * NT * 4; gid += stride) {
        int s = (int)(gid & 3);
        long bt = gid >> 2;
        int b = (int)(bt / NT), t = (int)(bt % NT);
        int id = ids[bt];
        const float* er = emb + (long)id * NE;
        bf16_t* dst = Xp + ((long)t * NB + b) * KX + s * 16;
#pragma unroll
        for (int j = 0; j < 16; ++j) {
            int e = s * 16 + j;
            dst[j] = (bf16_t)((e < NE) ? er[e] : 0.0f);
        }
    }
}

// ---------------- persistent LSTM kernel ----------------
// blk = role*8 + g. Roles 0..18: GEMM worker for hidden cols role*16..+15
// (all 4 gates) of group g (batch rows g*128..+127). Role 19: pred block
// (MFMA h_t @ U, U held as bf16 hi+lo register fragments for f32 accuracy).
// h ring: step t writes H[t&3], reads H[(t+3)&3]; pred t reads H[t&3];
// GEMM t gates on pflag(t-4) before overwriting. Local (same-XCD) mode:
// plain write-through stores + poll-exit L1-inv + plain loads through the
// XCD L2. Fallback: MALL agent atomics.
__global__ void __launch_bounds__(512, 2) lstm_persist(
    const float* __restrict__ bl, const bf16_t* __restrict__ WpT,
    bf16_t* Hbase,
    const bf16_t* __restrict__ Xp,
    unsigned* flgG, unsigned* flgP, unsigned* xcdA,
    const float* __restrict__ U, const float* __restrict__ b2,
    float* __restrict__ out)
{
    __shared__ __align__(16) unsigned char smem[64 * WCOL_STRIDE];   // 50176 B
    __shared__ int sLocalOK;
    const int blk = blockIdx.x;
    const int tid = threadIdx.x;
    const int g = blk & 7;
    const int c = blk >> 3;                      // role
    const int lane = tid & 63, wave = tid >> 6;

    // ---- publish my XCD; verify all 20 group members share it
    if (tid == 0)
        __hip_atomic_store(xcdA + blk, xcc_id() + 1u,
                           __ATOMIC_RELAXED, __HIP_MEMORY_SCOPE_AGENT);
    if (wave == 0) {
        unsigned v = 1u;
        for (;;) {
            if (lane < ROLES)
                v = coh_loadu(xcdA + (lane * NGRP + g));
            if (__all(v != 0)) break;
            __builtin_amdgcn_s_sleep(1);
        }
        unsigned ref = __shfl(v, 0, 64);
        int ok = __all(lane >= ROLES || v == ref);
        if (lane == 0) sLocalOK = ok;
    }

    unsigned* gBase = flgG + (long)g * NT * ROLES;
    unsigned* pBase = flgP + (long)g * NT;
    const size_t HSZ = (size_t)NB * KH;           // elements per h slot

    if (c < NCOLB) {
        // ================= GEMM worker =================
        // stage W slice into LDS (once): 64 cols (gate*16+mm), stride 784B
        for (int ch = tid; ch < 64 * 48; ch += 512) {
            int col = ch / 48, pq = ch % 48;
            int gt = col >> 4, mm = col & 15;
            int hc = c * 16 + mm;
            const uint4* src = (const uint4*)(WpT + (long)(gt * HP + hc) * KT) + pq;
            *(uint4*)(smem + col * WCOL_STRIDE + pq * 16) = *src;
        }

        const int m = lane & 15, quad = lane >> 4;
        const int rbase = g * 128 + wave * 16;   // this wave: rows rbase..rbase+15
        const int rowA  = rbase + m;
        const int hcOut = c * 16 + m;
        const bool colOK = (hcOut < NH);

        float bias[4] = {0.f, 0.f, 0.f, 0.f};
        if (colOK) {
#pragma unroll
            for (int gt = 0; gt < 4; ++gt) bias[gt] = bl[gt * NH + hcOut];
        }
        float cst[4] = {0.f, 0.f, 0.f, 0.f};

        __syncthreads();                         // W staged + sLocalOK visible
        const bool localOK = (sLocalOK != 0);

        // ---- t-invariant B fragments (h k-chunks 2..9) FORCED into VGPRs.
        // The asm "writes" each frag -> compiler cannot rematerialize from
        // LDS (r6/r9 VGPR=112 proved it silently did). 32 frags = 128 VGPRs.
        bf16x8 Bh[8][4];
#pragma unroll
        for (int kk = 0; kk < 8; ++kk)
#pragma unroll
            for (int gt = 0; gt < 4; ++gt) {
                Bh[kk][gt] = *(const bf16x8*)(smem + (gt * 16 + m) * WCOL_STRIDE
                                              + ((kk + 2) * 4 + quad) * 16);
                asm volatile("" : "+v"(Bh[kk][gt]));
            }

        for (int t = 0; t < NT; ++t) {
            // x fragments + x-part MFMAs BEFORE the wait (no h dependency)
            const bf16x8* xv = (const bf16x8*)(Xp + ((long)t * NB + rowA) * KX);
            bf16x8 ax[2];
#pragma unroll
            for (int kk = 0; kk < 2; ++kk) ax[kk] = xv[kk * 4 + quad];

            f32x4 acc[4];
#pragma unroll
            for (int gt = 0; gt < 4; ++gt) acc[gt] = (f32x4){0.f, 0.f, 0.f, 0.f};
#pragma unroll
            for (int kk = 0; kk < 2; ++kk) {
#pragma unroll
                for (int gt = 0; gt < 4; ++gt) {
                    bf16x8 b = *(const bf16x8*)(smem + (gt * 16 + m) * WCOL_STRIDE
                                                + (kk * 4 + quad) * 16);
                    acc[gt] = __builtin_amdgcn_mfma_f32_16x16x32_bf16(ax[kk], b, acc[gt], 0, 0, 0);
                }
            }

            // wait: 19 sibling h-flags of t-1; pred done reading h slot (t-4).
            // Local mode: inv_l1 per poll iteration == the freshness fence for
            // EVERYTHING read after the barrier (h lines can't re-enter L1
            // between wave0's last inv and the other waves' loads).
            if (t > 0) {
                if (wave == 0) {
                    const unsigned* gf = gBase + (long)(t - 1) * ROLES;
                    const bool needP = (t >= HSLOTS);
                    const unsigned* ap = (lane < NCOLB) ? (gf + lane)
                                                        : (pBase + (t - HSLOTS));
                    const bool active = (lane < NCOLB) || (lane == NCOLB && needP);
                    if (localOK) {
                        for (;;) {
                            inv_l1();
                            unsigned v = active ? *(const volatile unsigned*)ap : 1u;
                            if (__all(v != 0)) break;
                            __builtin_amdgcn_s_sleep(1);
                        }
                    } else {
                        for (;;) {
                            unsigned v = active ? coh_loadu(ap) : 1u;
                            if (__all(v != 0)) break;
                            __builtin_amdgcn_s_sleep(1);
                        }
                    }
                }
            }
            __syncthreads();
            __builtin_amdgcn_sched_barrier(0);

            const bf16_t* Hr = Hbase + (size_t)((t + 3) & 3) * HSZ;
            bf16_t*       Hw = Hbase + (size_t)(t & 3) * HSZ;

            // ---- h A-fragments (no per-wave inv: poll-exit inv covers; t=0
            // reads zeroed slot 3 with launch-fresh L1)
            const bf16_t* hp = Hr + (long)rowA * KH;
            bf16x8 ah[10];
            if (localOK) {
                const bf16x8* hv = (const bf16x8*)hp;
#pragma unroll
                for (int i = 0; i < 10; ++i) ah[i] = hv[i * 4 + quad];
            } else {
#pragma unroll
                for (int i = 0; i < 10; ++i) ah[i] = coh_load8(hp + (i * 4 + quad) * 8);
            }
            __builtin_amdgcn_sched_barrier(0);

            // h part: k-chunks 2..9 from registers, 10..11 from LDS
#pragma unroll
            for (int kk = 2; kk < 10; ++kk) {
#pragma unroll
                for (int gt = 0; gt < 4; ++gt)
                    acc[gt] = __builtin_amdgcn_mfma_f32_16x16x32_bf16(
                        ah[kk - 2], Bh[kk - 2][gt], acc[gt], 0, 0, 0);
            }
#pragma unroll
            for (int kk = 10; kk < 12; ++kk) {
#pragma unroll
                for (int gt = 0; gt < 4; ++gt) {
                    bf16x8 b = *(const bf16x8*)(smem + (gt * 16 + m) * WCOL_STRIDE
                                                + (kk * 4 + quad) * 16);
                    acc[gt] = __builtin_amdgcn_mfma_f32_16x16x32_bf16(ah[kk - 2], b, acc[gt], 0, 0, 0);
                }
            }

            // ---- gates + state update (C/D: col = lane&15, row = quad*4 + r)
            float hn_[4];
#pragma unroll
            for (int r = 0; r < 4; ++r) {
                float zi = acc[0][r] + bias[0];
                float zj = acc[1][r] + bias[1];
                float zf = acc[2][r] + bias[2];
                float zo = acc[3][r] + bias[3];
                float cn = cst[r] * fsig(zf + 1.0f) + fsig(zi) * ftanh(zj);
                cst[r] = cn;
                hn_[r] = ftanh(cn) * fsig(zo);
            }
            if (colOK) {
                if (localOK) {
#pragma unroll
                    for (int r = 0; r < 4; ++r)
                        Hw[(long)(rbase + quad * 4 + r) * KH + hcOut] = (bf16_t)hn_[r];
                } else {
#pragma unroll
                    for (int r = 0; r < 4; ++r)
                        coh_store16(Hw + (long)(rbase + quad * 4 + r) * KH + hcOut,
                                    (bf16_t)hn_[r]);
                }
            }

            __syncthreads();   // all waves' h stores drained (vmcnt 0 at barrier)
            if (tid == 0) {
                unsigned* fp = gBase + (long)t * ROLES + c;
                if (localOK) *(volatile unsigned*)fp = 1u;   // write-through -> L2
                else __hip_atomic_store(fp, 1u, __ATOMIC_RELAXED,
                                        __HIP_MEMORY_SCOPE_AGENT);
            }
        }
    } else {
        // ================= pred block: out[t] = h_t @ U + b2 via MFMA =========
        // U split into bf16 hi + bf16 lo (U = hi + lo): two MFMA accumulations
        // recover ~f32 accuracy. UT layouts col-major [n=16 pad][k=320 pad].
        bf16_t* UThi = (bf16_t*)smem;                 // 16*320*2 = 10240 B
        bf16_t* UTlo = (bf16_t*)(smem + 10240);       // 10240 B
        for (int i = tid; i < 16 * 320; i += 512) {
            int n = i / 320, k = i % 320;
            float v = (n < 5 && k < NH) ? U[k * 5 + n] : 0.0f;
            bf16_t hi = (bf16_t)v;
            UThi[i] = hi;
            UTlo[i] = (bf16_t)(v - (float)hi);
        }
        const int m = lane & 15, quad = lane >> 4;
        const float b2v = (m < 5) ? b2[m] : 0.0f;
        __syncthreads();
        const bool localOK = (sLocalOK != 0);

        // t-invariant U fragments in VGPRs (20 frags = 80 VGPRs, keep-alive)
        bf16x8 Bu[10][2];
#pragma unroll
        for (int kk = 0; kk < 10; ++kk) {
            Bu[kk][0] = *(const bf16x8*)(UThi + m * 320 + kk * 32 + quad * 8);
            asm volatile("" : "+v"(Bu[kk][0]));
            Bu[kk][1] = *(const bf16x8*)(UTlo + m * 320 + kk * 32 + quad * 8);
            asm volatile("" : "+v"(Bu[kk][1]));
        }
        const int row0 = g * 128 + wave * 16 + m;     // A row for this lane

        for (int t = 0; t < NT; ++t) {
            if (wave == 0) {
                const unsigned* gf = gBase + (long)t * ROLES;
                if (localOK) {
                    for (;;) {
                        inv_l1();
                        unsigned v = (lane < NCOLB) ? *(const volatile unsigned*)(gf + lane) : 1u;
                        if (__all(v != 0)) break;
                        __builtin_amdgcn_s_sleep(1);
                    }
                } else {
                    for (;;) {
                        unsigned v = (lane < NCOLB) ? coh_loadu(gf + lane) : 1u;
                        if (__all(v != 0)) break;
                        __builtin_amdgcn_s_sleep(1);
                    }
                }
            }
            __syncthreads();
            __builtin_amdgcn_sched_barrier(0);

            const bf16_t* Hs = Hbase + (size_t)(t & 3) * HSZ;
            const bf16_t* hp = Hs + (long)row0 * KH;
            bf16x8 ah[10];
            if (localOK) {
                const bf16x8* hv = (const bf16x8*)hp;
#pragma unroll
                for (int i = 0; i < 10; ++i) ah[i] = hv[i * 4 + quad];
            } else {
#pragma unroll
                for (int i = 0; i < 10; ++i) ah[i] = coh_load8(hp + (i * 4 + quad) * 8);
            }
            __builtin_amdgcn_sched_barrier(0);

            f32x4 acc = (f32x4){0.f, 0.f, 0.f, 0.f};
#pragma unroll
            for (int kk = 0; kk < 10; ++kk) {
                acc = __builtin_amdgcn_mfma_f32_16x16x32_bf16(ah[kk], Bu[kk][0], acc, 0, 0, 0);
                acc = __builtin_amdgcn_mfma_f32_16x16x32_bf16(ah[kk], Bu[kk][1], acc, 0, 0, 0);
            }

            // C/D: col = lane&15 (= class m, valid m<5), row = quad*4 + r
            if (m < 5) {
#pragma unroll
                for (int r = 0; r < 4; ++r) {
                    int row = g * 128 + wave * 16 + quad * 4 + r;
                    out[(long)t * (NB * 5) + row * 5 + m] = acc[r] + b2v;
                }
            }

            __syncthreads();   // all waves' h reads of slot t&3 complete
            if (tid == 0) {
                unsigned* fp = pBase + t;
                if (localOK) *(volatile unsigned*)fp = 1u;
                else __hip_atomic_store(fp, 1u, __ATOMIC_RELAXED,
                                        __HIP_MEMORY_SCOPE_AGENT);
            }
        }
    }
}

// ---------------- launcher ----------------
extern "C" void kernel_launch(void* const* d_in, const int* in_sizes, int n_in,
                              void* d_out, int out_size, void* d_ws, size_t ws_size,
                              hipStream_t stream) {
    const int* ids   = (const int*)d_in[0];
    const float* emb = (const float*)d_in[1];
    const float* W   = (const float*)d_in[2];
    const float* bl  = (const float*)d_in[3];
    const float* U   = (const float*)d_in[4];
    const float* b2  = (const float*)d_in[5];
    float* out = (float*)d_out;

    // ws layout (16B-aligned, ~19.4 MB):
    //   WpT   0         ..   983,040   (4*320*384*2)
    //   H[4]  983,040   .. 3,604,480   (4*1024*320*2)
    //   flgG  3,604,480 .. 3,681,280   (8*120*20*4)
    //   flgP  3,681,280 .. 3,685,120   (8*120*4)
    //   xcdA  3,685,120 .. 3,685,760   (160*4)
    //   Xp    3,685,760 .. 19,414,400  (120*1024*64*2)
    char* ws = (char*)d_ws;
    bf16_t*   WpT   = (bf16_t*)ws;
    bf16_t*   Hbase = (bf16_t*)(ws + 983040);
    unsigned* flgG  = (unsigned*)(ws + 3604480);
    unsigned* flgP  = (unsigned*)(ws + 3681280);
    unsigned* xcdA  = (unsigned*)(ws + 3685120);
    bf16_t*   Xp    = (bf16_t*)(ws + 3685760);

    // one fused prep launch: zero H/flgG/flgP/xcdA (168,920 uint4), pack W,
    // gather embeddings
    prep_all<<<2048, 256, 0, stream>>>(ids, emb, W, WpT,
                                       (uint4*)(ws + 983040), 168920, Xp);

    void* kargs[] = { (void*)&bl, (void*)&WpT, (void*)&Hbase, (void*)&Xp,
                      (void*)&flgG, (void*)&flgP, (void*)&xcdA,
                      (void*)&U, (void*)&b2, (void*)&out };
    hipError_t err = hipLaunchCooperativeKernel((const void*)lstm_persist,
                                                dim3(GRID), dim3(512), kargs, 0, stream);
    if (err != hipSuccess) {
        // co-residency holds anyway: 160 blocks <= 256 CUs, 50.2 KB LDS
        lstm_persist<<<GRID, 512, 0, stream>>>(bl, WpT, Hbase, Xp,
                                               flgG, flgP, xcdA, U, b2, out);
    }
}

// Round 12
// 641.515 us; speedup vs baseline: 4.6335x; 1.0027x over previous
//
#include <hip/hip_runtime.h>
#include <hip/hip_bf16.h>

// ROUND 12: r10-proven data path + counter sync in AGENT scope only.
// r11's workgroup-scope fetch_add(0) poll can be legalized into a plain
// (sc-bit-free) load -> stale L1 -> hang (same class as r7). Here:
// producers fetch_add(+1) agent-scope (fire-and-forget, proven primitive),
// consumers poll with ONE lane via agent atomic load until ==19. This cuts
// the r10 poller storm (19 blocks x 19 lanes on ~2 cache lines) to 19
// single-lane loads. Data path identical to r10 (plain write-through h
// stores + single inv_l1 after wait-exit + plain loads in local mode).
// Also: HSLOTS=8, bias in MFMA C-init, gates interleaved with h stores.

// Problem constants
#define NB 1024      // batch
#define NT 120       // seq len
#define NE 50        // embed
#define NH 300       // hidden
#define KX 64        // padded x K (50 -> 64): k-chunks 0..1
#define KH 320       // padded h K (300 -> 320): k-chunks 2..11
#define KT 384       // total padded K (12 chunks of 32)
#define HP 320       // padded h-cols per gate in WpT
#define NGRP 8       // row groups of 128 rows; group = blk & 7 (XCD-aligned)
#define NCOLB 19     // GEMM workers per group (19*16 = 304 >= 300 hidden cols)
#define ROLES 20     // 19 GEMM + 1 pred
#define GRID 160     // 8 groups * 20 roles; blk = role*8 + g
#define WCOL_STRIDE 784        // LDS W col stride: 768B data + 16B pad
#define HSLOTS 8     // h ring buffers; GEMM t gates pred-done(t-8)

typedef __bf16 bf16_t;
typedef __bf16 bf16x8 __attribute__((ext_vector_type(8)));
typedef float f32x4 __attribute__((ext_vector_type(4)));

// Fast gates via v_rcp_f32 (~1e-7 rel err, negligible vs bf16-h rounding).
__device__ __forceinline__ float fsig(float x) {
    return __builtin_amdgcn_rcpf(1.0f + __expf(-x));
}
__device__ __forceinline__ float ftanh(float x) {
    return fmaf(2.0f, __builtin_amdgcn_rcpf(1.0f + __expf(-2.0f * x)), -1.0f);
}

// ---- fallback (cross-XCD) transport: relaxed agent atomics (MALL) ----
__device__ __forceinline__ bf16x8 coh_load8(const bf16_t* p) {
    const unsigned long long* q = (const unsigned long long*)p;
    union { unsigned long long u[2]; bf16x8 v; } t;
    t.u[0] = __hip_atomic_load(q,     __ATOMIC_RELAXED, __HIP_MEMORY_SCOPE_AGENT);
    t.u[1] = __hip_atomic_load(q + 1, __ATOMIC_RELAXED, __HIP_MEMORY_SCOPE_AGENT);
    return t.v;
}
__device__ __forceinline__ void coh_store16(bf16_t* p, bf16_t h) {
    __hip_atomic_store((unsigned short*)p, __builtin_bit_cast(unsigned short, h),
                       __ATOMIC_RELAXED, __HIP_MEMORY_SCOPE_AGENT);
}
__device__ __forceinline__ unsigned coh_loadu(const unsigned* p) {
    return __hip_atomic_load(p, __ATOMIC_RELAXED, __HIP_MEMORY_SCOPE_AGENT);
}
// Counter bump: standard device-scope atomic add (proven primitive; result
// discarded -> non-returning global_atomic_add, cannot be demoted to a load).
__device__ __forceinline__ void cnt_bump(unsigned* p) {
    __hip_atomic_fetch_add(p, 1u, __ATOMIC_RELAXED, __HIP_MEMORY_SCOPE_AGENT);
}

// ---- local (same-XCD) transport helpers (proven r5-r10) ----
__device__ __forceinline__ void inv_l1() {
    asm volatile("buffer_inv sc0\n\ts_waitcnt vmcnt(0)" ::: "memory");
}
__device__ __forceinline__ unsigned xcc_id() {
    unsigned x;
    asm volatile("s_getreg_b32 %0, hwreg(HW_REG_XCC_ID)" : "=s"(x));
    return x & 0xfu;
}

// ---------------- fused prep kernel (one launch) ----------------
__global__ void prep_all(const int* __restrict__ ids, const float* __restrict__ emb,
                         const float* __restrict__ W,
                         bf16_t* __restrict__ WpT, uint4* __restrict__ zbase,
                         int nzero, bf16_t* __restrict__ Xp) {
    const long stride = (long)gridDim.x * 256;
    const long g0 = (long)blockIdx.x * 256 + threadIdx.x;

    for (long i = g0; i < nzero; i += stride)
        zbase[i] = make_uint4(0u, 0u, 0u, 0u);

    for (long gid = g0; gid < 4 * HP * KT; gid += stride) {
        int k = (int)(gid % KT);
        int col = (int)(gid / KT);
        int g = col / HP, hc = col % HP;
        int kp = -1;
        if (k < 50) kp = k;
        else if (k >= 64 && k < 364) kp = k - 14;
        float v = 0.0f;
        if (kp >= 0 && hc < NH) v = W[(long)kp * 1200 + g * NH + hc];
        WpT[gid] = (bf16_t)v;
    }

    for (long gid = g0; gid < (long)NB * NT * 4; gid += stride) {
        int s = (int)(gid & 3);
        long bt = gid >> 2;
        int b = (int)(bt / NT), t = (int)(bt % NT);
        int id = ids[bt];
        const float* er = emb + (long)id * NE;
        bf16_t* dst = Xp + ((long)t * NB + b) * KX + s * 16;
#pragma unroll
        for (int j = 0; j < 16; ++j) {
            int e = s * 16 + j;
            dst[j] = (bf16_t)((e < NE) ? er[e] : 0.0f);
        }
    }
}

// ---------------- persistent LSTM kernel ----------------
// blk = role*8 + g. Roles 0..18: GEMM worker for hidden cols role*16..+15
// (all 4 gates) of group g (rows g*128..+127). Role 19: pred block (MFMA
// h_t @ U with split-precision bf16 hi+lo U). h ring of 8 slots: step t
// writes slot t&7, reads slot (t-1)&7; pred t reads slot t&7; GEMM t waits
// gcnt[t-1]==19 and pcnt[t-8]>=1 before overwriting. Counters: agent-scope
// fetch_add / single-lane agent atomic-load poll. h data: local mode =
// plain write-through stores + one inv_l1 at wait-exit + plain L2 loads;
// fallback = MALL agent atomics.
__global__ void __launch_bounds__(512, 2) lstm_persist(
    const float* __restrict__ bl, const bf16_t* __restrict__ WpT,
    bf16_t* Hbase,
    const bf16_t* __restrict__ Xp,
    unsigned* gcnt, unsigned* pcnt, unsigned* xcdA,
    const float* __restrict__ U, const float* __restrict__ b2,
    float* __restrict__ out)
{
    __shared__ __align__(16) unsigned char smem[64 * WCOL_STRIDE];   // 50176 B
    __shared__ int sLocalOK;
    const int blk = blockIdx.x;
    const int tid = threadIdx.x;
    const int g = blk & 7;
    const int c = blk >> 3;                      // role
    const int lane = tid & 63, wave = tid >> 6;

    // ---- publish my XCD; verify all 20 group members share it
    if (tid == 0)
        __hip_atomic_store(xcdA + blk, xcc_id() + 1u,
                           __ATOMIC_RELAXED, __HIP_MEMORY_SCOPE_AGENT);
    if (wave == 0) {
        unsigned v = 1u;
        for (;;) {
            if (lane < ROLES)
                v = coh_loadu(xcdA + (lane * NGRP + g));
            if (__all(v != 0)) break;
            __builtin_amdgcn_s_sleep(1);
        }
        unsigned ref = __shfl(v, 0, 64);
        int ok = __all(lane >= ROLES || v == ref);
        if (lane == 0) sLocalOK = ok;
    }

    unsigned* gC = gcnt + (long)g * NT;
    unsigned* pC = pcnt + (long)g * NT;
    const size_t HSZ = (size_t)NB * KH;           // elements per h slot

    if (c < NCOLB) {
        // ================= GEMM worker =================
        // stage W slice into LDS (once): 64 cols (gate*16+mm), stride 784B
        for (int ch = tid; ch < 64 * 48; ch += 512) {
            int col = ch / 48, pq = ch % 48;
            int gt = col >> 4, mm = col & 15;
            int hc = c * 16 + mm;
            const uint4* src = (const uint4*)(WpT + (long)(gt * HP + hc) * KT) + pq;
            *(uint4*)(smem + col * WCOL_STRIDE + pq * 16) = *src;
        }

        const int m = lane & 15, quad = lane >> 4;
        const int rbase = g * 128 + wave * 16;   // this wave: rows rbase..rbase+15
        const int rowA  = rbase + m;
        const int hcOut = c * 16 + m;
        const bool colOK = (hcOut < NH);

        float bias[4] = {0.f, 0.f, 0.f, 0.f};
        if (colOK) {
#pragma unroll
            for (int gt = 0; gt < 4; ++gt) bias[gt] = bl[gt * NH + hcOut];
        }
        float cst[4] = {0.f, 0.f, 0.f, 0.f};

        __syncthreads();                         // W staged + sLocalOK visible
        const bool localOK = (sLocalOK != 0);

        // t-invariant B fragments (h k-chunks 2..9) pinned via asm keep-alive
        bf16x8 Bh[8][4];
#pragma unroll
        for (int kk = 0; kk < 8; ++kk)
#pragma unroll
            for (int gt = 0; gt < 4; ++gt) {
                Bh[kk][gt] = *(const bf16x8*)(smem + (gt * 16 + m) * WCOL_STRIDE
                                              + ((kk + 2) * 4 + quad) * 16);
                asm volatile("" : "+v"(Bh[kk][gt]));
            }

        for (int t = 0; t < NT; ++t) {
            // x fragments + x-part MFMAs BEFORE the wait (no h dependency).
            // acc C-init = bias (C/D col = lane&15 = hcOut; 4 regs = 4 rows,
            // same col -> same bias).
            const bf16x8* xv = (const bf16x8*)(Xp + ((long)t * NB + rowA) * KX);
            bf16x8 ax[2];
#pragma unroll
            for (int kk = 0; kk < 2; ++kk) ax[kk] = xv[kk * 4 + quad];

            f32x4 acc[4];
#pragma unroll
            for (int gt = 0; gt < 4; ++gt)
                acc[gt] = (f32x4){bias[gt], bias[gt], bias[gt], bias[gt]};
#pragma unroll
            for (int kk = 0; kk < 2; ++kk) {
#pragma unroll
                for (int gt = 0; gt < 4; ++gt) {
                    bf16x8 b = *(const bf16x8*)(smem + (gt * 16 + m) * WCOL_STRIDE
                                                + (kk * 4 + quad) * 16);
                    acc[gt] = __builtin_amdgcn_mfma_f32_16x16x32_bf16(ax[kk], b, acc[gt], 0, 0, 0);
                }
            }

            // wait: gcnt[t-1]==19 (h complete) and pcnt[t-8]>=1 (slot free).
            // Single-lane agent atomic-load polls (coherence-point-served,
            // cannot be stale; 19 blocks x 1 lane vs r10's 361 lane-pollers).
            if (t > 0) {
                if (wave == 0) {
                    unsigned* gcp = gC + (t - 1);
                    unsigned* pcp = pC + (t - HSLOTS);
                    const bool needP = (t >= HSLOTS);
                    for (;;) {
                        unsigned v = 19u;
                        if (lane == 0)               v = coh_loadu(gcp);
                        else if (lane == 1 && needP) v = 18u + coh_loadu(pcp);
                        if (__all(v >= 19u)) break;
                        __builtin_amdgcn_s_sleep(1);
                    }
                    if (localOK) inv_l1();       // fence: fresh L2 view for h
                }
            }
            __syncthreads();
            __builtin_amdgcn_sched_barrier(0);

            const bf16_t* Hr = Hbase + (size_t)((t + HSLOTS - 1) & (HSLOTS - 1)) * HSZ;
            bf16_t*       Hw = Hbase + (size_t)(t & (HSLOTS - 1)) * HSZ;

            // ---- h A-fragments
            const bf16_t* hp = Hr + (long)rowA * KH;
            bf16x8 ah[10];
            if (localOK) {
                const bf16x8* hv = (const bf16x8*)hp;
#pragma unroll
                for (int i = 0; i < 10; ++i) ah[i] = hv[i * 4 + quad];
            } else {
#pragma unroll
                for (int i = 0; i < 10; ++i) ah[i] = coh_load8(hp + (i * 4 + quad) * 8);
            }
            __builtin_amdgcn_sched_barrier(0);

            // h part: k-chunks 2..9 from registers, 10..11 from LDS
#pragma unroll
            for (int kk = 2; kk < 10; ++kk) {
#pragma unroll
                for (int gt = 0; gt < 4; ++gt)
                    acc[gt] = __builtin_amdgcn_mfma_f32_16x16x32_bf16(
                        ah[kk - 2], Bh[kk - 2][gt], acc[gt], 0, 0, 0);
            }
#pragma unroll
            for (int kk = 10; kk < 12; ++kk) {
#pragma unroll
                for (int gt = 0; gt < 4; ++gt) {
                    bf16x8 b = *(const bf16x8*)(smem + (gt * 16 + m) * WCOL_STRIDE
                                                + (kk * 4 + quad) * 16);
                    acc[gt] = __builtin_amdgcn_mfma_f32_16x16x32_bf16(ah[kk - 2], b, acc[gt], 0, 0, 0);
                }
            }

            // ---- gates + state update + store, interleaved per row so each
            // store's L2 drain overlaps the next row's transcendentals.
            // (C/D: col = lane&15, row = quad*4 + r)
#pragma unroll
            for (int r = 0; r < 4; ++r) {
                float zi = acc[0][r];
                float zj = acc[1][r];
                float zf = acc[2][r];
                float zo = acc[3][r];
                float cn = cst[r] * fsig(zf + 1.0f) + fsig(zi) * ftanh(zj);
                cst[r] = cn;
                float hn = ftanh(cn) * fsig(zo);
                if (colOK) {
                    bf16_t* dst = Hw + (long)(rbase + quad * 4 + r) * KH + hcOut;
                    if (localOK) *dst = (bf16_t)hn;
                    else coh_store16(dst, (bf16_t)hn);
                }
            }

            __syncthreads();   // all waves' h stores drained (vmcnt 0 at barrier)
            if (tid == 0) cnt_bump(gC + t);
        }
    } else {
        // ================= pred block: out[t] = h_t @ U + b2 via MFMA =========
        // U split into bf16 hi + lo (U = hi + lo) -> two MFMA accumulations.
        bf16_t* UThi = (bf16_t*)smem;                 // 16*320*2 = 10240 B
        bf16_t* UTlo = (bf16_t*)(smem + 10240);       // 10240 B
        for (int i = tid; i < 16 * 320; i += 512) {
            int n = i / 320, k = i % 320;
            float v = (n < 5 && k < NH) ? U[k * 5 + n] : 0.0f;
            bf16_t hi = (bf16_t)v;
            UThi[i] = hi;
            UTlo[i] = (bf16_t)(v - (float)hi);
        }
        const int m = lane & 15, quad = lane >> 4;
        const float b2v = (m < 5) ? b2[m] : 0.0f;
        __syncthreads();
        const bool localOK = (sLocalOK != 0);

        bf16x8 Bu[10][2];
#pragma unroll
        for (int kk = 0; kk < 10; ++kk) {
            Bu[kk][0] = *(const bf16x8*)(UThi + m * 320 + kk * 32 + quad * 8);
            asm volatile("" : "+v"(Bu[kk][0]));
            Bu[kk][1] = *(const bf16x8*)(UTlo + m * 320 + kk * 32 + quad * 8);
            asm volatile("" : "+v"(Bu[kk][1]));
        }
        const int row0 = g * 128 + wave * 16 + m;     // A row for this lane

        for (int t = 0; t < NT; ++t) {
            if (wave == 0) {
                unsigned* gcp = gC + t;
                for (;;) {
                    unsigned v = 19u;
                    if (lane == 0) v = coh_loadu(gcp);
                    if (__all(v >= 19u)) break;
                    __builtin_amdgcn_s_sleep(1);
                }
                if (localOK) inv_l1();
            }
            __syncthreads();
            __builtin_amdgcn_sched_barrier(0);

            const bf16_t* Hs = Hbase + (size_t)(t & (HSLOTS - 1)) * HSZ;
            const bf16_t* hp = Hs + (long)row0 * KH;
            bf16x8 ah[10];
            if (localOK) {
                const bf16x8* hv = (const bf16x8*)hp;
#pragma unroll
                for (int i = 0; i < 10; ++i) ah[i] = hv[i * 4 + quad];
            } else {
#pragma unroll
                for (int i = 0; i < 10; ++i) ah[i] = coh_load8(hp + (i * 4 + quad) * 8);
            }
            __builtin_amdgcn_sched_barrier(0);

            f32x4 acc = (f32x4){0.f, 0.f, 0.f, 0.f};
#pragma unroll
            for (int kk = 0; kk < 10; ++kk) {
                acc = __builtin_amdgcn_mfma_f32_16x16x32_bf16(ah[kk], Bu[kk][0], acc, 0, 0, 0);
                acc = __builtin_amdgcn_mfma_f32_16x16x32_bf16(ah[kk], Bu[kk][1], acc, 0, 0, 0);
            }

            // C/D: col = lane&15 (= class m, valid m<5), row = quad*4 + r
            if (m < 5) {
#pragma unroll
                for (int r = 0; r < 4; ++r) {
                    int row = g * 128 + wave * 16 + quad * 4 + r;
                    out[(long)t * (NB * 5) + row * 5 + m] = acc[r] + b2v;
                }
            }

            __syncthreads();   // all waves' h reads of slot t&7 complete
            if (tid == 0) cnt_bump(pC + t);
        }
    }
}

// ---------------- launcher ----------------
extern "C" void kernel_launch(void* const* d_in, const int* in_sizes, int n_in,
                              void* d_out, int out_size, void* d_ws, size_t ws_size,
                              hipStream_t stream) {
    const int* ids   = (const int*)d_in[0];
    const float* emb = (const float*)d_in[1];
    const float* W   = (const float*)d_in[2];
    const float* bl  = (const float*)d_in[3];
    const float* U   = (const float*)d_in[4];
    const float* b2  = (const float*)d_in[5];
    float* out = (float*)d_out;

    // ws layout (16B-aligned, ~22 MB):
    //   WpT   0         ..   983,040   (4*320*384*2)
    //   H[8]  983,040   .. 6,225,920   (8*1024*320*2)
    //   gcnt  6,225,920 .. 6,229,760   (8*120*4)
    //   pcnt  6,229,760 .. 6,233,600   (8*120*4)
    //   xcdA  6,233,600 .. 6,234,240   (160*4)
    //   Xp    6,234,240 .. 21,962,880  (120*1024*64*2)
    char* ws = (char*)d_ws;
    bf16_t*   WpT   = (bf16_t*)ws;
    bf16_t*   Hbase = (bf16_t*)(ws + 983040);
    unsigned* gcnt  = (unsigned*)(ws + 6225920);
    unsigned* pcnt  = (unsigned*)(ws + 6229760);
    unsigned* xcdA  = (unsigned*)(ws + 6233600);
    bf16_t*   Xp    = (bf16_t*)(ws + 6234240);

    // one fused prep launch: zero H/gcnt/pcnt/xcdA (328,200 uint4 =
    // 5,251,200 B), pack W, gather embeddings
    prep_all<<<2048, 256, 0, stream>>>(ids, emb, W, WpT,
                                       (uint4*)(ws + 983040), 328200, Xp);

    void* kargs[] = { (void*)&bl, (void*)&WpT, (void*)&Hbase, (void*)&Xp,
                      (void*)&gcnt, (void*)&pcnt, (void*)&xcdA,
                      (void*)&U, (void*)&b2, (void*)&out };
    hipError_t err = hipLaunchCooperativeKernel((const void*)lstm_persist,
                                                dim3(GRID), dim3(512), kargs, 0, stream);
    if (err != hipSuccess) {
        // co-residency holds anyway: 160 blocks <= 256 CUs, 50.2 KB LDS
        lstm_persist<<<GRID, 512, 0, stream>>>(bl, WpT, Hbase, Xp,
                                               gcnt, pcnt, xcdA, U, b2, out);
    }
}